// Round 9
// baseline (219.125 us; speedup 1.0000x reference)
//
#include <hip/hip_runtime.h>

// GNN encoder: input MLP + LN, 2x SAGEConv(mean) + ReLU + residual + LN, classifier MLP.
// Round 9: gather fused INTO the SAGE kernels (agg buffer + 2 dispatches eliminated).
//  - k_sage0_f / k_sage_cls_f: 64 rows/block, LDS = WTl(32K)|WTr(32K)|agg-tile(16K) = 80 KB,
//    gather phase (quarter-wave/node, 4-deep) -> swizzled LDS agg -> MFMA A-operand.
//    Ping-pong hbA->hbB (fusion makes in-place h update racy across blocks).
//  - k_sage_cls_f phase B: th over WTl, Wc1 over WTr, Wc2 over agg region.
//  - k_mlp unchanged (round 8); CSR multi-block scan unchanged.

namespace {

constexpr int NN = 50000;
constexpr int EE = 640000;
constexpr int HH = 128;
constexpr int CC = 40;
constexpr int SCAN_NB = (NN + 255) / 256;  // 196

typedef unsigned short u16;
typedef __attribute__((ext_vector_type(8))) short s16x8;
typedef __attribute__((ext_vector_type(8))) unsigned short u16x8;
typedef __attribute__((ext_vector_type(4))) float f32x4;

__device__ __forceinline__ float b2f(u16 h) {
  unsigned int u = ((unsigned int)h) << 16;
  return __builtin_bit_cast(float, u);
}
__device__ __forceinline__ u16 f2b(float f) {
  unsigned int u = __builtin_bit_cast(unsigned int, f);
  u += 0x7FFFu + ((u >> 16) & 1u);
  return (u16)(u >> 16);
}

// ---- swizzled LDS tile: row n, 16B-granule k0; slot = k0 ^ (n&15) ----
__device__ __forceinline__ s16x8 ldsw(const u16* base, int n, int k0) {
  return *reinterpret_cast<const s16x8*>(base + n * 128 + (((k0 ^ n) & 15) << 3));
}
__device__ __forceinline__ void stsw(u16* base, int r, int c, u16 v) {
  base[r * 128 + ((((c >> 3) ^ r) & 15) << 3) + (c & 7)] = v;
}
template <int NGRAN>
__device__ __forceinline__ void stage(const u16* __restrict__ src, u16* dst, int tid) {
#pragma unroll
  for (int i = 0; i < (NGRAN + 255) / 256; ++i) {
    const int gi = i * 256 + tid;
    if ((NGRAN & 255) == 0 || gi < NGRAN) {
      const int n = gi >> 4, k0 = gi & 15;
      const u16x8 v = *reinterpret_cast<const u16x8*>(src + gi * 8);
      *reinterpret_cast<u16x8*>(dst + n * 128 + (((k0 ^ n) & 15) << 3)) = v;
    }
  }
}

// ---------------- CSR build ----------------
__global__ void k_degree(const int* __restrict__ ei, int* __restrict__ cnt) {
  int e = blockIdx.x * 256 + threadIdx.x;
  if (e < EE) atomicAdd(&cnt[ei[EE + e]], 1);
}

__global__ void k_scan_block(const int* __restrict__ cnt, int* __restrict__ rowptr,
                             int* __restrict__ bsum, float* __restrict__ inv) {
  __shared__ int s[256];
  const int t = threadIdx.x;
  const int i = blockIdx.x * 256 + t;
  const int v = i < NN ? cnt[i] : 0;
  s[t] = v;
  __syncthreads();
  for (int off = 1; off < 256; off <<= 1) {
    int add = t >= off ? s[t - off] : 0;
    __syncthreads();
    s[t] += add;
    __syncthreads();
  }
  if (i < NN) {
    rowptr[i] = s[t] - v;
    inv[i] = v > 0 ? 1.0f / (float)v : 0.0f;
  }
  if (t == 255) bsum[blockIdx.x] = s[255];
}

__global__ void k_scan_tops(int* __restrict__ bsum) {
  __shared__ int s[256];
  const int t = threadIdx.x;
  const int v = t < SCAN_NB ? bsum[t] : 0;
  s[t] = v;
  __syncthreads();
  for (int off = 1; off < 256; off <<= 1) {
    int add = t >= off ? s[t - off] : 0;
    __syncthreads();
    s[t] += add;
    __syncthreads();
  }
  if (t < SCAN_NB) bsum[t] = s[t] - v;
}

__global__ void k_scan_add(int* __restrict__ rowptr, const int* __restrict__ bsum) {
  const int i = blockIdx.x * 256 + threadIdx.x;
  if (i < NN) rowptr[i] += bsum[blockIdx.x];
  if (i == 0) rowptr[NN] = EE;
}

__global__ void k_fill(const int* __restrict__ ei, const int* __restrict__ rowptr,
                       int* __restrict__ cursor, int* __restrict__ col) {
  int e = blockIdx.x * 256 + threadIdx.x;
  if (e >= EE) return;
  int s = ei[e];
  int d = ei[EE + e];
  int pos = atomicAdd(&cursor[d], 1);
  col[rowptr[d] + pos] = s;
}

// transpose+cast all weights into wt slots {pw1,pw2,wl0,wl1,wr0,wr1,cw1,cw2T}
__global__ void k_prep_w(const float* __restrict__ pw1, const float* __restrict__ pw2,
                         const float* __restrict__ swl, const float* __restrict__ swr,
                         const float* __restrict__ cw1, const float* __restrict__ cw2,
                         u16* __restrict__ wt) {
  int flat = blockIdx.x * 256 + threadIdx.x;
  const int SEVEN = 7 * 16384;
  if (flat < SEVEN) {
    int id = flat >> 14;
    int off = flat & 16383;
    int n = off >> 7, k = off & 127;
    const float* s;
    switch (id) {
      case 0: s = pw1; break;
      case 1: s = pw2; break;
      case 2: s = swl; break;
      case 3: s = swl + 16384; break;
      case 4: s = swr; break;
      case 5: s = swr + 16384; break;
      default: s = cw1; break;
    }
    wt[(size_t)id * 16384 + n * 128 + k] = f2b(s[k * 128 + n]);
  } else {
    int off = flat - SEVEN;
    if (off < CC * 128) {
      int n = off >> 7, k = off & 127;
      wt[(size_t)7 * 16384 + n * 128 + k] = f2b(cw2[k * CC + n]);
    }
  }
}

// ---- in-kernel gather phase: quarter-wave per node, 4 nodes each, -> LDS agg tile ----
__device__ __forceinline__ void gather_to_lds(
    const u16* __restrict__ hb, const int* __restrict__ rowptr,
    const int* __restrict__ col, const float* __restrict__ inv,
    u16* ag, int node0, int tid) {
  const int qw = tid >> 4;      // 0..15
  const int c = tid & 15;       // 16B granule
  const int cl = c * 8;
#pragma unroll
  for (int p = 0; p < 4; ++p) {
    const int lr = p * 16 + qw;           // block-local row 0..63
    const int node = node0 + lr;
    float a[8] = {0.f, 0.f, 0.f, 0.f, 0.f, 0.f, 0.f, 0.f};
    float sc = 0.f;
    if (node < NN) {
      sc = inv[node];
      int i = rowptr[node];
      const int end = rowptr[node + 1];
      for (; i + 4 <= end; i += 4) {
        const int s0 = col[i], s1 = col[i + 1], s2 = col[i + 2], s3 = col[i + 3];
        const u16x8 v0 = *reinterpret_cast<const u16x8*>(&hb[(size_t)s0 * HH + cl]);
        const u16x8 v1 = *reinterpret_cast<const u16x8*>(&hb[(size_t)s1 * HH + cl]);
        const u16x8 v2 = *reinterpret_cast<const u16x8*>(&hb[(size_t)s2 * HH + cl]);
        const u16x8 v3 = *reinterpret_cast<const u16x8*>(&hb[(size_t)s3 * HH + cl]);
#pragma unroll
        for (int k = 0; k < 8; ++k)
          a[k] += (b2f(v0[k]) + b2f(v1[k])) + (b2f(v2[k]) + b2f(v3[k]));
      }
      for (; i < end; ++i) {
        const u16x8 v0 = *reinterpret_cast<const u16x8*>(&hb[(size_t)col[i] * HH + cl]);
#pragma unroll
        for (int k = 0; k < 8; ++k) a[k] += b2f(v0[k]);
      }
    }
    u16x8 o;
#pragma unroll
    for (int k = 0; k < 8; ++k) o[k] = f2b(a[k] * sc);
    *reinterpret_cast<u16x8*>(ag + lr * 128 + (((c ^ lr) & 15) << 3)) = o;
  }
}

// ---------------- fused input MLP: h = LN(relu(x@pw1+pb1)@pw2+pb2) ----------------
__global__ __launch_bounds__(256) void k_mlp(
    const float* __restrict__ x, const u16* __restrict__ WT1,
    const float* __restrict__ pb1, const u16* __restrict__ WT2,
    const float* __restrict__ pb2, const float* __restrict__ lg,
    const float* __restrict__ lb, u16* __restrict__ hb) {
  __shared__ u16 lds[32768];
  u16* wreg = lds;
  u16* t1r = lds + 16384;
  const int tid = threadIdx.x;
  const int wv = tid >> 6, ln = tid & 63;
  const int lrow = ln & 15, kg = ln >> 4;
  const int tbase = blockIdx.x * 128 + wv * 32;
  const int lb0 = wv * 32;
  const int ar0 = min(tbase + lrow, NN - 1);
  const int ar1 = min(tbase + 16 + lrow, NN - 1);

  stage<2048>(WT1, wreg, tid);
  __syncthreads();

  f32x4 acc0[8], acc1[8];
#pragma unroll
  for (int cf = 0; cf < 8; ++cf) {
    acc0[cf] = (f32x4){0.f, 0.f, 0.f, 0.f};
    acc1[cf] = (f32x4){0.f, 0.f, 0.f, 0.f};
  }
#pragma unroll
  for (int ks = 0; ks < 4; ++ks) {
    const float4* p0 = reinterpret_cast<const float4*>(x + (size_t)ar0 * 128 + ks * 32 + kg * 8);
    const float4* p1 = reinterpret_cast<const float4*>(x + (size_t)ar1 * 128 + ks * 32 + kg * 8);
    float4 x0 = p0[0], x1 = p0[1], y0 = p1[0], y1 = p1[1];
    s16x8 a0, a1;
    a0[0] = (short)f2b(x0.x); a0[1] = (short)f2b(x0.y); a0[2] = (short)f2b(x0.z); a0[3] = (short)f2b(x0.w);
    a0[4] = (short)f2b(x1.x); a0[5] = (short)f2b(x1.y); a0[6] = (short)f2b(x1.z); a0[7] = (short)f2b(x1.w);
    a1[0] = (short)f2b(y0.x); a1[1] = (short)f2b(y0.y); a1[2] = (short)f2b(y0.z); a1[3] = (short)f2b(y0.w);
    a1[4] = (short)f2b(y1.x); a1[5] = (short)f2b(y1.y); a1[6] = (short)f2b(y1.z); a1[7] = (short)f2b(y1.w);
#pragma unroll
    for (int cf = 0; cf < 8; ++cf) {
      const s16x8 bf = ldsw(wreg, cf * 16 + lrow, ks * 4 + kg);
      acc0[cf] = __builtin_amdgcn_mfma_f32_16x16x32_bf16(a0, bf, acc0[cf], 0, 0, 0);
      acc1[cf] = __builtin_amdgcn_mfma_f32_16x16x32_bf16(a1, bf, acc1[cf], 0, 0, 0);
    }
  }
  {
    float bb[8];
#pragma unroll
    for (int cf = 0; cf < 8; ++cf) bb[cf] = pb1[cf * 16 + lrow];
#pragma unroll
    for (int t = 0; t < 2; ++t)
#pragma unroll
      for (int j = 0; j < 4; ++j) {
        const int lr = lb0 + t * 16 + kg * 4 + j;
#pragma unroll
        for (int cf = 0; cf < 8; ++cf)
          stsw(t1r, lr, cf * 16 + lrow, f2b(fmaxf((t ? acc1[cf][j] : acc0[cf][j]) + bb[cf], 0.0f)));
      }
  }
  __syncthreads();
  stage<2048>(WT2, wreg, tid);
  __syncthreads();

  f32x4 c0[8], c1[8];
#pragma unroll
  for (int cf = 0; cf < 8; ++cf) {
    c0[cf] = (f32x4){0.f, 0.f, 0.f, 0.f};
    c1[cf] = (f32x4){0.f, 0.f, 0.f, 0.f};
  }
#pragma unroll
  for (int ks = 0; ks < 4; ++ks) {
    const s16x8 a0 = ldsw(t1r, lb0 + lrow, ks * 4 + kg);
    const s16x8 a1 = ldsw(t1r, lb0 + 16 + lrow, ks * 4 + kg);
#pragma unroll
    for (int cf = 0; cf < 8; ++cf) {
      const s16x8 bf = ldsw(wreg, cf * 16 + lrow, ks * 4 + kg);
      c0[cf] = __builtin_amdgcn_mfma_f32_16x16x32_bf16(a0, bf, c0[cf], 0, 0, 0);
      c1[cf] = __builtin_amdgcn_mfma_f32_16x16x32_bf16(a1, bf, c1[cf], 0, 0, 0);
    }
  }

  float bb[8], gm[8], gb[8];
#pragma unroll
  for (int cf = 0; cf < 8; ++cf) {
    const int c = cf * 16 + lrow;
    bb[cf] = pb2[c];
    gm[cf] = lg[c];
    gb[cf] = lb[c];
  }
#pragma unroll
  for (int t = 0; t < 2; ++t)
#pragma unroll
    for (int j = 0; j < 4; ++j) {
      const int r = tbase + t * 16 + kg * 4 + j;
      float v[8];
#pragma unroll
      for (int cf = 0; cf < 8; ++cf) v[cf] = (t ? c1[cf][j] : c0[cf][j]) + bb[cf];
      float s = 0.f;
#pragma unroll
      for (int cf = 0; cf < 8; ++cf) s += v[cf];
      s += __shfl_xor(s, 1); s += __shfl_xor(s, 2);
      s += __shfl_xor(s, 4); s += __shfl_xor(s, 8);
      const float mu = s * (1.0f / 128);
      float q = 0.f;
#pragma unroll
      for (int cf = 0; cf < 8; ++cf) { const float d = v[cf] - mu; q += d * d; }
      q += __shfl_xor(q, 1); q += __shfl_xor(q, 2);
      q += __shfl_xor(q, 4); q += __shfl_xor(q, 8);
      const float istd = rsqrtf(q * (1.0f / 128) + 1e-5f);
      if (r < NN) {
#pragma unroll
        for (int cf = 0; cf < 8; ++cf)
          hb[(size_t)r * 128 + cf * 16 + lrow] = f2b((v[cf] - mu) * istd * gm[cf] + gb[cf]);
      }
    }
}

// ---------------- fused SAGE layer 0 (gather + conv + LN), hbA -> hbB ----------------
__global__ __launch_bounds__(256) void k_sage0_f(
    const u16* __restrict__ hbin, const int* __restrict__ rowptr,
    const int* __restrict__ col, const float* __restrict__ inv,
    const u16* __restrict__ WTl, const u16* __restrict__ WTr,
    const float* __restrict__ bl, const float* __restrict__ lg,
    const float* __restrict__ lb, u16* __restrict__ hbout) {
  __shared__ u16 lds[40960];
  u16* wl = lds;
  u16* wr = lds + 16384;
  u16* ag = lds + 32768;  // 64x128 agg tile
  const int tid = threadIdx.x;
  const int wv = tid >> 6, ln = tid & 63;
  const int lrow = ln & 15, kg = ln >> 4;
  const int tbase = blockIdx.x * 64 + wv * 16;
  const int ar = min(tbase + lrow, NN - 1);

  stage<2048>(WTl, wl, tid);
  stage<2048>(WTr, wr, tid);
  gather_to_lds(hbin, rowptr, col, inv, ag, blockIdx.x * 64, tid);
  __syncthreads();

  f32x4 acc[8];
#pragma unroll
  for (int cf = 0; cf < 8; ++cf) acc[cf] = (f32x4){0.f, 0.f, 0.f, 0.f};
#pragma unroll
  for (int ks = 0; ks < 4; ++ks) {
    const s16x8 g0 = ldsw(ag, wv * 16 + lrow, ks * 4 + kg);
    const s16x8 h0 = *reinterpret_cast<const s16x8*>(hbin + (size_t)ar * 128 + ks * 32 + kg * 8);
#pragma unroll
    for (int cf = 0; cf < 8; ++cf) {
      const s16x8 bwl = ldsw(wl, cf * 16 + lrow, ks * 4 + kg);
      const s16x8 bwr = ldsw(wr, cf * 16 + lrow, ks * 4 + kg);
      acc[cf] = __builtin_amdgcn_mfma_f32_16x16x32_bf16(g0, bwl, acc[cf], 0, 0, 0);
      acc[cf] = __builtin_amdgcn_mfma_f32_16x16x32_bf16(h0, bwr, acc[cf], 0, 0, 0);
    }
  }

  float bb[8], gm[8], gb[8];
#pragma unroll
  for (int cf = 0; cf < 8; ++cf) {
    const int c = cf * 16 + lrow;
    bb[cf] = bl[c];
    gm[cf] = lg[c];
    gb[cf] = lb[c];
  }
#pragma unroll
  for (int j = 0; j < 4; ++j) {
    const int r = tbase + kg * 4 + j;
    const int rs = r < NN ? r : NN - 1;
    float v[8];
#pragma unroll
    for (int cf = 0; cf < 8; ++cf) {
      const int c = cf * 16 + lrow;
      v[cf] = b2f(hbin[(size_t)rs * 128 + c]) + fmaxf(acc[cf][j] + bb[cf], 0.0f);
    }
    float s = 0.f;
#pragma unroll
    for (int cf = 0; cf < 8; ++cf) s += v[cf];
    s += __shfl_xor(s, 1); s += __shfl_xor(s, 2);
    s += __shfl_xor(s, 4); s += __shfl_xor(s, 8);
    const float mu = s * (1.0f / 128);
    float q = 0.f;
#pragma unroll
    for (int cf = 0; cf < 8; ++cf) { const float d = v[cf] - mu; q += d * d; }
    q += __shfl_xor(q, 1); q += __shfl_xor(q, 2);
    q += __shfl_xor(q, 4); q += __shfl_xor(q, 8);
    const float istd = rsqrtf(q * (1.0f / 128) + 1e-5f);
    if (r < NN) {
#pragma unroll
      for (int cf = 0; cf < 8; ++cf)
        hbout[(size_t)r * 128 + cf * 16 + lrow] = f2b((v[cf] - mu) * istd * gm[cf] + gb[cf]);
    }
  }
}

// ---------------- fused SAGE layer 1 + classifier, hbB -> out_h + logits ----------------
// LDS phase A: wl=WTl, wr=WTr, ag=agg tile. Phase B: wl=th tile, wr=Wc1, ag=Wc2.
__global__ __launch_bounds__(256) void k_sage_cls_f(
    const u16* __restrict__ hbin, const int* __restrict__ rowptr,
    const int* __restrict__ col, const float* __restrict__ inv,
    const u16* __restrict__ WTl, const u16* __restrict__ WTr,
    const float* __restrict__ bl, const float* __restrict__ lg,
    const float* __restrict__ lb,
    const u16* __restrict__ Wc1, const float* __restrict__ cb1,
    const u16* __restrict__ Wc2, const float* __restrict__ cb2,
    float* __restrict__ out_h, float* __restrict__ logits) {
  __shared__ u16 lds[40960];
  u16* wl = lds;
  u16* wr = lds + 16384;
  u16* ag = lds + 32768;
  const int tid = threadIdx.x;
  const int wv = tid >> 6, ln = tid & 63;
  const int lrow = ln & 15, kg = ln >> 4;
  const int tbase = blockIdx.x * 64 + wv * 16;
  const int lb0 = wv * 16;
  const int ar = min(tbase + lrow, NN - 1);

  stage<2048>(WTl, wl, tid);
  stage<2048>(WTr, wr, tid);
  gather_to_lds(hbin, rowptr, col, inv, ag, blockIdx.x * 64, tid);
  __syncthreads();

  f32x4 acc[8];
#pragma unroll
  for (int cf = 0; cf < 8; ++cf) acc[cf] = (f32x4){0.f, 0.f, 0.f, 0.f};
#pragma unroll
  for (int ks = 0; ks < 4; ++ks) {
    const s16x8 g0 = ldsw(ag, wv * 16 + lrow, ks * 4 + kg);
    const s16x8 h0 = *reinterpret_cast<const s16x8*>(hbin + (size_t)ar * 128 + ks * 32 + kg * 8);
#pragma unroll
    for (int cf = 0; cf < 8; ++cf) {
      const s16x8 bwl = ldsw(wl, cf * 16 + lrow, ks * 4 + kg);
      const s16x8 bwr = ldsw(wr, cf * 16 + lrow, ks * 4 + kg);
      acc[cf] = __builtin_amdgcn_mfma_f32_16x16x32_bf16(g0, bwl, acc[cf], 0, 0, 0);
      acc[cf] = __builtin_amdgcn_mfma_f32_16x16x32_bf16(h0, bwr, acc[cf], 0, 0, 0);
    }
  }
  __syncthreads();  // all reads of wl/wr/ag done

  {
    float bb[8], gm[8], gb[8];
#pragma unroll
    for (int cf = 0; cf < 8; ++cf) {
      const int c = cf * 16 + lrow;
      bb[cf] = bl[c];
      gm[cf] = lg[c];
      gb[cf] = lb[c];
    }
#pragma unroll
    for (int j = 0; j < 4; ++j) {
      const int r = tbase + kg * 4 + j;
      const int rs = r < NN ? r : NN - 1;
      const int lr = lb0 + kg * 4 + j;
      float v[8];
#pragma unroll
      for (int cf = 0; cf < 8; ++cf) {
        const int c = cf * 16 + lrow;
        v[cf] = b2f(hbin[(size_t)rs * 128 + c]) + fmaxf(acc[cf][j] + bb[cf], 0.0f);
      }
      float s = 0.f;
#pragma unroll
      for (int cf = 0; cf < 8; ++cf) s += v[cf];
      s += __shfl_xor(s, 1); s += __shfl_xor(s, 2);
      s += __shfl_xor(s, 4); s += __shfl_xor(s, 8);
      const float mu = s * (1.0f / 128);
      float q = 0.f;
#pragma unroll
      for (int cf = 0; cf < 8; ++cf) { const float d = v[cf] - mu; q += d * d; }
      q += __shfl_xor(q, 1); q += __shfl_xor(q, 2);
      q += __shfl_xor(q, 4); q += __shfl_xor(q, 8);
      const float istd = rsqrtf(q * (1.0f / 128) + 1e-5f);
#pragma unroll
      for (int cf = 0; cf < 8; ++cf) {
        const int c = cf * 16 + lrow;
        const float o = (v[cf] - mu) * istd * gm[cf] + gb[cf];
        stsw(wl, lr, c, f2b(o));
        if (r < NN) out_h[(size_t)r * 128 + c] = o;
      }
    }
  }
  stage<2048>(Wc1, wr, tid);
  stage<640>(Wc2, ag, tid);
  __syncthreads();

  // classifier: wave-private 16-row th tile in wl
  float cb1v[8];
#pragma unroll
  for (int cf = 0; cf < 8; ++cf) cb1v[cf] = cb1[cf * 16 + lrow];

  f32x4 a3[8];
#pragma unroll
  for (int cf = 0; cf < 8; ++cf) a3[cf] = (f32x4){0.f, 0.f, 0.f, 0.f};
#pragma unroll
  for (int ks = 0; ks < 4; ++ks) {
    const s16x8 a = ldsw(wl, lb0 + lrow, ks * 4 + kg);
#pragma unroll
    for (int cf = 0; cf < 8; ++cf) {
      const s16x8 bf = ldsw(wr, cf * 16 + lrow, ks * 4 + kg);
      a3[cf] = __builtin_amdgcn_mfma_f32_16x16x32_bf16(a, bf, a3[cf], 0, 0, 0);
    }
  }
#pragma unroll
  for (int j = 0; j < 4; ++j)
#pragma unroll
    for (int cf = 0; cf < 8; ++cf)
      stsw(wl, lb0 + kg * 4 + j, cf * 16 + lrow, f2b(fmaxf(a3[cf][j] + cb1v[cf], 0.0f)));
  __syncthreads();

  f32x4 a2[3];
#pragma unroll
  for (int cf = 0; cf < 3; ++cf) a2[cf] = (f32x4){0.f, 0.f, 0.f, 0.f};
#pragma unroll
  for (int ks = 0; ks < 4; ++ks) {
    const s16x8 a = ldsw(wl, lb0 + lrow, ks * 4 + kg);
#pragma unroll
    for (int cf = 0; cf < 3; ++cf) {
      const int bn = min(cf * 16 + lrow, CC - 1);
      const s16x8 bf = ldsw(ag, bn, ks * 4 + kg);
      a2[cf] = __builtin_amdgcn_mfma_f32_16x16x32_bf16(a, bf, a2[cf], 0, 0, 0);
    }
  }
#pragma unroll
  for (int j = 0; j < 4; ++j) {
    const int r = tbase + kg * 4 + j;
    if (r < NN) {
#pragma unroll
      for (int cf = 0; cf < 3; ++cf) {
        const int c = cf * 16 + lrow;
        if (c < CC) logits[(size_t)r * CC + c] = a2[cf][j] + cb2[c];
      }
    }
  }
}

}  // namespace

extern "C" void kernel_launch(void* const* d_in, const int* in_sizes, int n_in,
                              void* d_out, int out_size, void* d_ws, size_t ws_size,
                              hipStream_t stream) {
  (void)in_sizes; (void)n_in; (void)out_size; (void)ws_size;
  const float* x   = (const float*)d_in[0];
  const int*   ei  = (const int*)d_in[1];
  const float* pw1 = (const float*)d_in[2];
  const float* pb1 = (const float*)d_in[3];
  const float* pw2 = (const float*)d_in[4];
  const float* pb2 = (const float*)d_in[5];
  const float* ing = (const float*)d_in[6];
  const float* inb = (const float*)d_in[7];
  const float* swl = (const float*)d_in[8];
  const float* sbl = (const float*)d_in[9];
  const float* swr = (const float*)d_in[10];
  const float* lng = (const float*)d_in[11];
  const float* lnb = (const float*)d_in[12];
  const float* cw1 = (const float*)d_in[13];
  const float* cb1 = (const float*)d_in[14];
  const float* cw2 = (const float*)d_in[15];
  const float* cb2 = (const float*)d_in[16];

  float* out_logits = (float*)d_out;
  float* out_h = out_logits + (size_t)NN * CC;

  const size_t NNH = (size_t)NN * HH;
  u16*   hbA  = (u16*)d_ws;                // 12.8 MB
  u16*   hbB  = hbA + NNH;                 // 12.8 MB
  u16*   wt   = hbB + NNH;                 // 256 KB
  int*   cnt    = (int*)(wt + 8 * 16384);  // NN
  int*   cursor = cnt + NN;                // NN (adjacent: single memset)
  float* inv    = (float*)(cursor + NN);   // NN
  int*   rowptr = (int*)(inv + NN);        // NN+1
  int*   bsum   = rowptr + NN + 1;         // 256
  int*   colarr = bsum + 256;              // EE

  // ---- CSR build ----
  hipMemsetAsync(cnt, 0, 2 * NN * sizeof(int), stream);
  k_degree<<<(EE + 255) / 256, 256, 0, stream>>>(ei, cnt);
  k_scan_block<<<SCAN_NB, 256, 0, stream>>>(cnt, rowptr, bsum, inv);
  k_scan_tops<<<1, 256, 0, stream>>>(bsum);
  k_scan_add<<<SCAN_NB, 256, 0, stream>>>(rowptr, bsum);
  k_fill<<<(EE + 255) / 256, 256, 0, stream>>>(ei, rowptr, cursor, colarr);
  k_prep_w<<<(7 * 16384 + CC * 128 + 255) / 256, 256, 0, stream>>>(
      pw1, pw2, swl, swr, cw1, cw2, wt);

  // h = LN(relu(x@pw1+pb1)@pw2+pb2)   -> hbA
  k_mlp<<<(NN + 127) / 128, 256, 0, stream>>>(
      x, wt + 0 * 16384, pb1, wt + 1 * 16384, pb2, ing, inb, hbA);

  const int SG = (NN + 63) / 64;  // 782
  // layer 0: hbA -> hbB (gather fused)
  k_sage0_f<<<SG, 256, 0, stream>>>(
      hbA, rowptr, colarr, inv, wt + 2 * 16384, wt + 4 * 16384, sbl, lng, lnb, hbB);
  // layer 1 + classifier: hbB -> out_h + logits (gather fused)
  k_sage_cls_f<<<SG, 256, 0, stream>>>(
      hbB, rowptr, colarr, inv, wt + 3 * 16384, wt + 5 * 16384,
      sbl + HH, lng + HH, lnb + HH,
      wt + 6 * 16384, cb1, wt + 7 * 16384, cb2, out_h, out_logits);
}

// Round 10
// 188.724 us; speedup vs baseline: 1.1611x; 1.1611x over previous
//
#include <hip/hip_runtime.h>

// GNN encoder: input MLP + LN, 2x SAGEConv(mean) + ReLU + residual + LN, classifier MLP.
// Round 10: revert round-9 gather fusion (regression: 80KB LDS starved the latency-bound
// gather phase of TLP). Round-8 structure + two tweaks:
//  - k_gather_q: 8 edge-rows in flight per lane (was 4)
//  - scan_tops merged into scan_add (each block locally scans the 196 block sums)
// Dense kernels (round 8): 128 rows/block, weights staged in swizzled LDS, 2 row-tiles/wave.

namespace {

constexpr int NN = 50000;
constexpr int EE = 640000;
constexpr int HH = 128;
constexpr int CC = 40;
constexpr int SCAN_NB = (NN + 255) / 256;  // 196

typedef unsigned short u16;
typedef __attribute__((ext_vector_type(8))) short s16x8;
typedef __attribute__((ext_vector_type(8))) unsigned short u16x8;
typedef __attribute__((ext_vector_type(4))) float f32x4;

__device__ __forceinline__ float b2f(u16 h) {
  unsigned int u = ((unsigned int)h) << 16;
  return __builtin_bit_cast(float, u);
}
__device__ __forceinline__ u16 f2b(float f) {
  unsigned int u = __builtin_bit_cast(unsigned int, f);
  u += 0x7FFFu + ((u >> 16) & 1u);
  return (u16)(u >> 16);
}

// ---- swizzled LDS tile: row n, 16B-granule k0; slot = k0 ^ (n&15) ----
__device__ __forceinline__ s16x8 ldsw(const u16* base, int n, int k0) {
  return *reinterpret_cast<const s16x8*>(base + n * 128 + (((k0 ^ n) & 15) << 3));
}
__device__ __forceinline__ void stsw(u16* base, int r, int c, u16 v) {
  base[r * 128 + ((((c >> 3) ^ r) & 15) << 3) + (c & 7)] = v;
}
template <int NGRAN>
__device__ __forceinline__ void stage(const u16* __restrict__ src, u16* dst, int tid) {
#pragma unroll
  for (int i = 0; i < (NGRAN + 255) / 256; ++i) {
    const int gi = i * 256 + tid;
    if ((NGRAN & 255) == 0 || gi < NGRAN) {
      const int n = gi >> 4, k0 = gi & 15;
      const u16x8 v = *reinterpret_cast<const u16x8*>(src + gi * 8);
      *reinterpret_cast<u16x8*>(dst + n * 128 + (((k0 ^ n) & 15) << 3)) = v;
    }
  }
}

// ---------------- CSR build ----------------
__global__ void k_degree(const int* __restrict__ ei, int* __restrict__ cnt) {
  int e = blockIdx.x * 256 + threadIdx.x;
  if (e < EE) atomicAdd(&cnt[ei[EE + e]], 1);
}

__global__ void k_scan_block(const int* __restrict__ cnt, int* __restrict__ rowptr,
                             int* __restrict__ bsum, float* __restrict__ inv) {
  __shared__ int s[256];
  const int t = threadIdx.x;
  const int i = blockIdx.x * 256 + t;
  const int v = i < NN ? cnt[i] : 0;
  s[t] = v;
  __syncthreads();
  for (int off = 1; off < 256; off <<= 1) {
    int add = t >= off ? s[t - off] : 0;
    __syncthreads();
    s[t] += add;
    __syncthreads();
  }
  if (i < NN) {
    rowptr[i] = s[t] - v;
    inv[i] = v > 0 ? 1.0f / (float)v : 0.0f;
  }
  if (t == 255) bsum[blockIdx.x] = s[255];
}

// merged tops-scan + add: each block scans bsum locally, adds its exclusive prefix
__global__ void k_scan_add(int* __restrict__ rowptr, const int* __restrict__ bsum) {
  __shared__ int s[256];
  const int t = threadIdx.x;
  const int v = t < SCAN_NB ? bsum[t] : 0;
  s[t] = v;
  __syncthreads();
  for (int off = 1; off < 256; off <<= 1) {
    int add = t >= off ? s[t - off] : 0;
    __syncthreads();
    s[t] += add;
    __syncthreads();
  }
  const int boff = blockIdx.x == 0 ? 0 : s[blockIdx.x - 1];
  const int i = blockIdx.x * 256 + t;
  if (i < NN) rowptr[i] += boff;
  if (i == 0) rowptr[NN] = EE;
}

__global__ void k_fill(const int* __restrict__ ei, const int* __restrict__ rowptr,
                       int* __restrict__ cursor, int* __restrict__ col) {
  int e = blockIdx.x * 256 + threadIdx.x;
  if (e >= EE) return;
  int s = ei[e];
  int d = ei[EE + e];
  int pos = atomicAdd(&cursor[d], 1);
  col[rowptr[d] + pos] = s;
}

// transpose+cast all weights into wt slots {pw1,pw2,wl0,wl1,wr0,wr1,cw1,cw2T}
__global__ void k_prep_w(const float* __restrict__ pw1, const float* __restrict__ pw2,
                         const float* __restrict__ swl, const float* __restrict__ swr,
                         const float* __restrict__ cw1, const float* __restrict__ cw2,
                         u16* __restrict__ wt) {
  int flat = blockIdx.x * 256 + threadIdx.x;
  const int SEVEN = 7 * 16384;
  if (flat < SEVEN) {
    int id = flat >> 14;
    int off = flat & 16383;
    int n = off >> 7, k = off & 127;
    const float* s;
    switch (id) {
      case 0: s = pw1; break;
      case 1: s = pw2; break;
      case 2: s = swl; break;
      case 3: s = swl + 16384; break;
      case 4: s = swr; break;
      case 5: s = swr + 16384; break;
      default: s = cw1; break;
    }
    wt[(size_t)id * 16384 + n * 128 + k] = f2b(s[k * 128 + n]);
  } else {
    int off = flat - SEVEN;
    if (off < CC * 128) {
      int n = off >> 7, k = off & 127;
      wt[(size_t)7 * 16384 + n * 128 + k] = f2b(cw2[k * CC + n]);
    }
  }
}

// ---------------- aggregation: quarter-wave per node, 8 edges in flight ----------------
__global__ __launch_bounds__(256) void k_gather_q(
    const u16* __restrict__ hb, const int* __restrict__ rowptr,
    const int* __restrict__ col, const float* __restrict__ inv,
    u16* __restrict__ agg) {
  const int tid = threadIdx.x;
  const int node = blockIdx.x * 16 + (tid >> 4);
  if (node >= NN) return;
  const int ln = tid & 15;
  const int cl = ln * 8;
  const int start = rowptr[node];
  const int end = rowptr[node + 1];
  float a[8] = {0.f, 0.f, 0.f, 0.f, 0.f, 0.f, 0.f, 0.f};
  int i = start;
  for (; i + 8 <= end; i += 8) {
    const int s0 = col[i], s1 = col[i + 1], s2 = col[i + 2], s3 = col[i + 3];
    const int s4 = col[i + 4], s5 = col[i + 5], s6 = col[i + 6], s7 = col[i + 7];
    const u16x8 v0 = *reinterpret_cast<const u16x8*>(&hb[(size_t)s0 * HH + cl]);
    const u16x8 v1 = *reinterpret_cast<const u16x8*>(&hb[(size_t)s1 * HH + cl]);
    const u16x8 v2 = *reinterpret_cast<const u16x8*>(&hb[(size_t)s2 * HH + cl]);
    const u16x8 v3 = *reinterpret_cast<const u16x8*>(&hb[(size_t)s3 * HH + cl]);
    const u16x8 v4 = *reinterpret_cast<const u16x8*>(&hb[(size_t)s4 * HH + cl]);
    const u16x8 v5 = *reinterpret_cast<const u16x8*>(&hb[(size_t)s5 * HH + cl]);
    const u16x8 v6 = *reinterpret_cast<const u16x8*>(&hb[(size_t)s6 * HH + cl]);
    const u16x8 v7 = *reinterpret_cast<const u16x8*>(&hb[(size_t)s7 * HH + cl]);
#pragma unroll
    for (int k = 0; k < 8; ++k)
      a[k] += ((b2f(v0[k]) + b2f(v1[k])) + (b2f(v2[k]) + b2f(v3[k]))) +
              ((b2f(v4[k]) + b2f(v5[k])) + (b2f(v6[k]) + b2f(v7[k])));
  }
  if (i + 4 <= end) {
    const int s0 = col[i], s1 = col[i + 1], s2 = col[i + 2], s3 = col[i + 3];
    const u16x8 v0 = *reinterpret_cast<const u16x8*>(&hb[(size_t)s0 * HH + cl]);
    const u16x8 v1 = *reinterpret_cast<const u16x8*>(&hb[(size_t)s1 * HH + cl]);
    const u16x8 v2 = *reinterpret_cast<const u16x8*>(&hb[(size_t)s2 * HH + cl]);
    const u16x8 v3 = *reinterpret_cast<const u16x8*>(&hb[(size_t)s3 * HH + cl]);
#pragma unroll
    for (int k = 0; k < 8; ++k)
      a[k] += (b2f(v0[k]) + b2f(v1[k])) + (b2f(v2[k]) + b2f(v3[k]));
    i += 4;
  }
  for (; i < end; ++i) {
    const u16x8 v0 = *reinterpret_cast<const u16x8*>(&hb[(size_t)col[i] * HH + cl]);
#pragma unroll
    for (int k = 0; k < 8; ++k) a[k] += b2f(v0[k]);
  }
  const float sc = inv[node];
  u16x8 o;
#pragma unroll
  for (int k = 0; k < 8; ++k) o[k] = f2b(a[k] * sc);
  *reinterpret_cast<u16x8*>(&agg[(size_t)node * HH + cl]) = o;
}

// ---------------- fused input MLP: h = LN(relu(x@pw1+pb1)@pw2+pb2) ----------------
// LDS: [0,16384) = W (WT1 then WT2), [16384,32768) = t1 tile (128x128 swizzled)
__global__ __launch_bounds__(256) void k_mlp(
    const float* __restrict__ x, const u16* __restrict__ WT1,
    const float* __restrict__ pb1, const u16* __restrict__ WT2,
    const float* __restrict__ pb2, const float* __restrict__ lg,
    const float* __restrict__ lb, u16* __restrict__ hb) {
  __shared__ u16 lds[32768];
  u16* wreg = lds;
  u16* t1r = lds + 16384;
  const int tid = threadIdx.x;
  const int wv = tid >> 6, ln = tid & 63;
  const int lrow = ln & 15, kg = ln >> 4;
  const int tbase = blockIdx.x * 128 + wv * 32;
  const int lb0 = wv * 32;
  const int ar0 = min(tbase + lrow, NN - 1);
  const int ar1 = min(tbase + 16 + lrow, NN - 1);

  stage<2048>(WT1, wreg, tid);
  __syncthreads();

  f32x4 acc0[8], acc1[8];
#pragma unroll
  for (int cf = 0; cf < 8; ++cf) {
    acc0[cf] = (f32x4){0.f, 0.f, 0.f, 0.f};
    acc1[cf] = (f32x4){0.f, 0.f, 0.f, 0.f};
  }
#pragma unroll
  for (int ks = 0; ks < 4; ++ks) {
    const float4* p0 = reinterpret_cast<const float4*>(x + (size_t)ar0 * 128 + ks * 32 + kg * 8);
    const float4* p1 = reinterpret_cast<const float4*>(x + (size_t)ar1 * 128 + ks * 32 + kg * 8);
    float4 x0 = p0[0], x1 = p0[1], y0 = p1[0], y1 = p1[1];
    s16x8 a0, a1;
    a0[0] = (short)f2b(x0.x); a0[1] = (short)f2b(x0.y); a0[2] = (short)f2b(x0.z); a0[3] = (short)f2b(x0.w);
    a0[4] = (short)f2b(x1.x); a0[5] = (short)f2b(x1.y); a0[6] = (short)f2b(x1.z); a0[7] = (short)f2b(x1.w);
    a1[0] = (short)f2b(y0.x); a1[1] = (short)f2b(y0.y); a1[2] = (short)f2b(y0.z); a1[3] = (short)f2b(y0.w);
    a1[4] = (short)f2b(y1.x); a1[5] = (short)f2b(y1.y); a1[6] = (short)f2b(y1.z); a1[7] = (short)f2b(y1.w);
#pragma unroll
    for (int cf = 0; cf < 8; ++cf) {
      const s16x8 bf = ldsw(wreg, cf * 16 + lrow, ks * 4 + kg);
      acc0[cf] = __builtin_amdgcn_mfma_f32_16x16x32_bf16(a0, bf, acc0[cf], 0, 0, 0);
      acc1[cf] = __builtin_amdgcn_mfma_f32_16x16x32_bf16(a1, bf, acc1[cf], 0, 0, 0);
    }
  }
  {
    float bb[8];
#pragma unroll
    for (int cf = 0; cf < 8; ++cf) bb[cf] = pb1[cf * 16 + lrow];
#pragma unroll
    for (int t = 0; t < 2; ++t)
#pragma unroll
      for (int j = 0; j < 4; ++j) {
        const int lr = lb0 + t * 16 + kg * 4 + j;
#pragma unroll
        for (int cf = 0; cf < 8; ++cf)
          stsw(t1r, lr, cf * 16 + lrow, f2b(fmaxf((t ? acc1[cf][j] : acc0[cf][j]) + bb[cf], 0.0f)));
      }
  }
  __syncthreads();
  stage<2048>(WT2, wreg, tid);
  __syncthreads();

  f32x4 c0[8], c1[8];
#pragma unroll
  for (int cf = 0; cf < 8; ++cf) {
    c0[cf] = (f32x4){0.f, 0.f, 0.f, 0.f};
    c1[cf] = (f32x4){0.f, 0.f, 0.f, 0.f};
  }
#pragma unroll
  for (int ks = 0; ks < 4; ++ks) {
    const s16x8 a0 = ldsw(t1r, lb0 + lrow, ks * 4 + kg);
    const s16x8 a1 = ldsw(t1r, lb0 + 16 + lrow, ks * 4 + kg);
#pragma unroll
    for (int cf = 0; cf < 8; ++cf) {
      const s16x8 bf = ldsw(wreg, cf * 16 + lrow, ks * 4 + kg);
      c0[cf] = __builtin_amdgcn_mfma_f32_16x16x32_bf16(a0, bf, c0[cf], 0, 0, 0);
      c1[cf] = __builtin_amdgcn_mfma_f32_16x16x32_bf16(a1, bf, c1[cf], 0, 0, 0);
    }
  }

  float bb[8], gm[8], gb[8];
#pragma unroll
  for (int cf = 0; cf < 8; ++cf) {
    const int c = cf * 16 + lrow;
    bb[cf] = pb2[c];
    gm[cf] = lg[c];
    gb[cf] = lb[c];
  }
#pragma unroll
  for (int t = 0; t < 2; ++t)
#pragma unroll
    for (int j = 0; j < 4; ++j) {
      const int r = tbase + t * 16 + kg * 4 + j;
      float v[8];
#pragma unroll
      for (int cf = 0; cf < 8; ++cf) v[cf] = (t ? c1[cf][j] : c0[cf][j]) + bb[cf];
      float s = 0.f;
#pragma unroll
      for (int cf = 0; cf < 8; ++cf) s += v[cf];
      s += __shfl_xor(s, 1); s += __shfl_xor(s, 2);
      s += __shfl_xor(s, 4); s += __shfl_xor(s, 8);
      const float mu = s * (1.0f / 128);
      float q = 0.f;
#pragma unroll
      for (int cf = 0; cf < 8; ++cf) { const float d = v[cf] - mu; q += d * d; }
      q += __shfl_xor(q, 1); q += __shfl_xor(q, 2);
      q += __shfl_xor(q, 4); q += __shfl_xor(q, 8);
      const float istd = rsqrtf(q * (1.0f / 128) + 1e-5f);
      if (r < NN) {
#pragma unroll
        for (int cf = 0; cf < 8; ++cf)
          hb[(size_t)r * 128 + cf * 16 + lrow] = f2b((v[cf] - mu) * istd * gm[cf] + gb[cf]);
      }
    }
}

// ---------------- SAGE layer 0: h' = LN(h + relu(agg@WL + bl + h@WR)) -> hb ----------------
__global__ __launch_bounds__(256) void k_sage0(
    const u16* __restrict__ agg, const u16* __restrict__ hb,
    const u16* __restrict__ WTl, const u16* __restrict__ WTr,
    const float* __restrict__ bl, const float* __restrict__ lg,
    const float* __restrict__ lb, u16* __restrict__ hb_out) {
  __shared__ u16 lds[32768];
  u16* wl = lds;
  u16* wr = lds + 16384;
  const int tid = threadIdx.x;
  const int wv = tid >> 6, ln = tid & 63;
  const int lrow = ln & 15, kg = ln >> 4;
  const int tbase = blockIdx.x * 128 + wv * 32;
  const int ar0 = min(tbase + lrow, NN - 1);
  const int ar1 = min(tbase + 16 + lrow, NN - 1);

  stage<2048>(WTl, wl, tid);
  stage<2048>(WTr, wr, tid);
  __syncthreads();

  f32x4 acc0[8], acc1[8];
#pragma unroll
  for (int cf = 0; cf < 8; ++cf) {
    acc0[cf] = (f32x4){0.f, 0.f, 0.f, 0.f};
    acc1[cf] = (f32x4){0.f, 0.f, 0.f, 0.f};
  }
#pragma unroll
  for (int ks = 0; ks < 4; ++ks) {
    const s16x8 g0 = *reinterpret_cast<const s16x8*>(agg + (size_t)ar0 * 128 + ks * 32 + kg * 8);
    const s16x8 g1 = *reinterpret_cast<const s16x8*>(agg + (size_t)ar1 * 128 + ks * 32 + kg * 8);
    const s16x8 h0 = *reinterpret_cast<const s16x8*>(hb + (size_t)ar0 * 128 + ks * 32 + kg * 8);
    const s16x8 h1 = *reinterpret_cast<const s16x8*>(hb + (size_t)ar1 * 128 + ks * 32 + kg * 8);
#pragma unroll
    for (int cf = 0; cf < 8; ++cf) {
      const s16x8 bwl = ldsw(wl, cf * 16 + lrow, ks * 4 + kg);
      const s16x8 bwr = ldsw(wr, cf * 16 + lrow, ks * 4 + kg);
      acc0[cf] = __builtin_amdgcn_mfma_f32_16x16x32_bf16(g0, bwl, acc0[cf], 0, 0, 0);
      acc0[cf] = __builtin_amdgcn_mfma_f32_16x16x32_bf16(h0, bwr, acc0[cf], 0, 0, 0);
      acc1[cf] = __builtin_amdgcn_mfma_f32_16x16x32_bf16(g1, bwl, acc1[cf], 0, 0, 0);
      acc1[cf] = __builtin_amdgcn_mfma_f32_16x16x32_bf16(h1, bwr, acc1[cf], 0, 0, 0);
    }
  }

  float bb[8], gm[8], gb[8];
#pragma unroll
  for (int cf = 0; cf < 8; ++cf) {
    const int c = cf * 16 + lrow;
    bb[cf] = bl[c];
    gm[cf] = lg[c];
    gb[cf] = lb[c];
  }
#pragma unroll
  for (int t = 0; t < 2; ++t)
#pragma unroll
    for (int j = 0; j < 4; ++j) {
      const int r = tbase + t * 16 + kg * 4 + j;
      const int rs = r < NN ? r : NN - 1;
      float v[8];
#pragma unroll
      for (int cf = 0; cf < 8; ++cf) {
        const int c = cf * 16 + lrow;
        v[cf] = b2f(hb[(size_t)rs * 128 + c]) +
                fmaxf((t ? acc1[cf][j] : acc0[cf][j]) + bb[cf], 0.0f);
      }
      float s = 0.f;
#pragma unroll
      for (int cf = 0; cf < 8; ++cf) s += v[cf];
      s += __shfl_xor(s, 1); s += __shfl_xor(s, 2);
      s += __shfl_xor(s, 4); s += __shfl_xor(s, 8);
      const float mu = s * (1.0f / 128);
      float q = 0.f;
#pragma unroll
      for (int cf = 0; cf < 8; ++cf) { const float d = v[cf] - mu; q += d * d; }
      q += __shfl_xor(q, 1); q += __shfl_xor(q, 2);
      q += __shfl_xor(q, 4); q += __shfl_xor(q, 8);
      const float istd = rsqrtf(q * (1.0f / 128) + 1e-5f);
      if (r < NN) {
#pragma unroll
        for (int cf = 0; cf < 8; ++cf)
          hb_out[(size_t)r * 128 + cf * 16 + lrow] = f2b((v[cf] - mu) * istd * gm[cf] + gb[cf]);
      }
    }
}

// ---------------- SAGE layer 1 + classifier fused ----------------
// LDS: [0,16384)=WTl -> th tile; [16384,32768)=WTr -> Wc1; [32768,37888)=Wc2
__global__ __launch_bounds__(256) void k_sage_cls(
    const u16* __restrict__ agg, const u16* __restrict__ hb,
    const u16* __restrict__ WTl, const u16* __restrict__ WTr,
    const float* __restrict__ bl, const float* __restrict__ lg,
    const float* __restrict__ lb,
    const u16* __restrict__ Wc1, const float* __restrict__ cb1,
    const u16* __restrict__ Wc2, const float* __restrict__ cb2,
    float* __restrict__ out_h, float* __restrict__ logits) {
  __shared__ u16 lds[37888];
  u16* wl = lds;          // phase A: WTl ; phase B: th tile (128x128)
  u16* wr = lds + 16384;  // phase A: WTr ; phase B: Wc1
  u16* w2 = lds + 32768;  // Wc2 (40x128)
  const int tid = threadIdx.x;
  const int wv = tid >> 6, ln = tid & 63;
  const int lrow = ln & 15, kg = ln >> 4;
  const int tbase = blockIdx.x * 128 + wv * 32;
  const int lb0 = wv * 32;
  const int ar0 = min(tbase + lrow, NN - 1);
  const int ar1 = min(tbase + 16 + lrow, NN - 1);

  stage<2048>(WTl, wl, tid);
  stage<2048>(WTr, wr, tid);
  stage<640>(Wc2, w2, tid);
  __syncthreads();

  f32x4 acc0[8], acc1[8];
#pragma unroll
  for (int cf = 0; cf < 8; ++cf) {
    acc0[cf] = (f32x4){0.f, 0.f, 0.f, 0.f};
    acc1[cf] = (f32x4){0.f, 0.f, 0.f, 0.f};
  }
#pragma unroll
  for (int ks = 0; ks < 4; ++ks) {
    const s16x8 g0 = *reinterpret_cast<const s16x8*>(agg + (size_t)ar0 * 128 + ks * 32 + kg * 8);
    const s16x8 g1 = *reinterpret_cast<const s16x8*>(agg + (size_t)ar1 * 128 + ks * 32 + kg * 8);
    const s16x8 h0 = *reinterpret_cast<const s16x8*>(hb + (size_t)ar0 * 128 + ks * 32 + kg * 8);
    const s16x8 h1 = *reinterpret_cast<const s16x8*>(hb + (size_t)ar1 * 128 + ks * 32 + kg * 8);
#pragma unroll
    for (int cf = 0; cf < 8; ++cf) {
      const s16x8 bwl = ldsw(wl, cf * 16 + lrow, ks * 4 + kg);
      const s16x8 bwr = ldsw(wr, cf * 16 + lrow, ks * 4 + kg);
      acc0[cf] = __builtin_amdgcn_mfma_f32_16x16x32_bf16(g0, bwl, acc0[cf], 0, 0, 0);
      acc0[cf] = __builtin_amdgcn_mfma_f32_16x16x32_bf16(h0, bwr, acc0[cf], 0, 0, 0);
      acc1[cf] = __builtin_amdgcn_mfma_f32_16x16x32_bf16(g1, bwl, acc1[cf], 0, 0, 0);
      acc1[cf] = __builtin_amdgcn_mfma_f32_16x16x32_bf16(h1, bwr, acc1[cf], 0, 0, 0);
    }
  }
  __syncthreads();  // all waves done reading WTl/WTr

  {
    float bb[8], gm[8], gb[8];
#pragma unroll
    for (int cf = 0; cf < 8; ++cf) {
      const int c = cf * 16 + lrow;
      bb[cf] = bl[c];
      gm[cf] = lg[c];
      gb[cf] = lb[c];
    }
#pragma unroll
    for (int t = 0; t < 2; ++t)
#pragma unroll
      for (int j = 0; j < 4; ++j) {
        const int r = tbase + t * 16 + kg * 4 + j;
        const int rs = r < NN ? r : NN - 1;
        const int lr = lb0 + t * 16 + kg * 4 + j;
        float v[8];
#pragma unroll
        for (int cf = 0; cf < 8; ++cf) {
          const int c = cf * 16 + lrow;
          v[cf] = b2f(hb[(size_t)rs * 128 + c]) +
                  fmaxf((t ? acc1[cf][j] : acc0[cf][j]) + bb[cf], 0.0f);
        }
        float s = 0.f;
#pragma unroll
        for (int cf = 0; cf < 8; ++cf) s += v[cf];
        s += __shfl_xor(s, 1); s += __shfl_xor(s, 2);
        s += __shfl_xor(s, 4); s += __shfl_xor(s, 8);
        const float mu = s * (1.0f / 128);
        float q = 0.f;
#pragma unroll
        for (int cf = 0; cf < 8; ++cf) { const float d = v[cf] - mu; q += d * d; }
        q += __shfl_xor(q, 1); q += __shfl_xor(q, 2);
        q += __shfl_xor(q, 4); q += __shfl_xor(q, 8);
        const float istd = rsqrtf(q * (1.0f / 128) + 1e-5f);
#pragma unroll
        for (int cf = 0; cf < 8; ++cf) {
          const int c = cf * 16 + lrow;
          const float o = (v[cf] - mu) * istd * gm[cf] + gb[cf];
          stsw(wl, lr, c, f2b(o));
          if (r < NN) out_h[(size_t)r * 128 + c] = o;
        }
      }
  }
  stage<2048>(Wc1, wr, tid);  // Wc1 over WTr (all reads done at barrier above)
  __syncthreads();

  // classifier: per wave, its own two 16-row th tiles
  float cb1v[8];
#pragma unroll
  for (int cf = 0; cf < 8; ++cf) cb1v[cf] = cb1[cf * 16 + lrow];

#pragma unroll
  for (int t = 0; t < 2; ++t) {
    const int rb = lb0 + t * 16;
    f32x4 a3[8];
#pragma unroll
    for (int cf = 0; cf < 8; ++cf) a3[cf] = (f32x4){0.f, 0.f, 0.f, 0.f};
#pragma unroll
    for (int ks = 0; ks < 4; ++ks) {
      const s16x8 a = ldsw(wl, rb + lrow, ks * 4 + kg);
#pragma unroll
      for (int cf = 0; cf < 8; ++cf) {
        const s16x8 bf = ldsw(wr, cf * 16 + lrow, ks * 4 + kg);
        a3[cf] = __builtin_amdgcn_mfma_f32_16x16x32_bf16(a, bf, a3[cf], 0, 0, 0);
      }
    }
    // t3 overwrites this wave's own th rows
#pragma unroll
    for (int j = 0; j < 4; ++j)
#pragma unroll
      for (int cf = 0; cf < 8; ++cf)
        stsw(wl, rb + kg * 4 + j, cf * 16 + lrow, f2b(fmaxf(a3[cf][j] + cb1v[cf], 0.0f)));

    f32x4 a2[3];
#pragma unroll
    for (int cf = 0; cf < 3; ++cf) a2[cf] = (f32x4){0.f, 0.f, 0.f, 0.f};
#pragma unroll
    for (int ks = 0; ks < 4; ++ks) {
      const s16x8 a = ldsw(wl, rb + lrow, ks * 4 + kg);
#pragma unroll
      for (int cf = 0; cf < 3; ++cf) {
        const int bn = min(cf * 16 + lrow, CC - 1);
        const s16x8 bf = ldsw(w2, bn, ks * 4 + kg);
        a2[cf] = __builtin_amdgcn_mfma_f32_16x16x32_bf16(a, bf, a2[cf], 0, 0, 0);
      }
    }
#pragma unroll
    for (int j = 0; j < 4; ++j) {
      const int r = tbase + t * 16 + kg * 4 + j;
      if (r < NN) {
#pragma unroll
        for (int cf = 0; cf < 3; ++cf) {
          const int c = cf * 16 + lrow;
          if (c < CC) logits[(size_t)r * CC + c] = a2[cf][j] + cb2[c];
        }
      }
    }
  }
}

}  // namespace

extern "C" void kernel_launch(void* const* d_in, const int* in_sizes, int n_in,
                              void* d_out, int out_size, void* d_ws, size_t ws_size,
                              hipStream_t stream) {
  (void)in_sizes; (void)n_in; (void)out_size; (void)ws_size;
  const float* x   = (const float*)d_in[0];
  const int*   ei  = (const int*)d_in[1];
  const float* pw1 = (const float*)d_in[2];
  const float* pb1 = (const float*)d_in[3];
  const float* pw2 = (const float*)d_in[4];
  const float* pb2 = (const float*)d_in[5];
  const float* ing = (const float*)d_in[6];
  const float* inb = (const float*)d_in[7];
  const float* swl = (const float*)d_in[8];
  const float* sbl = (const float*)d_in[9];
  const float* swr = (const float*)d_in[10];
  const float* lng = (const float*)d_in[11];
  const float* lnb = (const float*)d_in[12];
  const float* cw1 = (const float*)d_in[13];
  const float* cb1 = (const float*)d_in[14];
  const float* cw2 = (const float*)d_in[15];
  const float* cb2 = (const float*)d_in[16];

  float* out_logits = (float*)d_out;
  float* out_h = out_logits + (size_t)NN * CC;

  const size_t NNH = (size_t)NN * HH;
  u16*   hb   = (u16*)d_ws;                // 12.8 MB
  u16*   bufA = hb + NNH;                  // 12.8 MB (agg)
  u16*   wt   = bufA + NNH;                // 256 KB
  int*   cnt    = (int*)(wt + 8 * 16384);  // NN
  int*   cursor = cnt + NN;                // NN (adjacent: single memset)
  float* inv    = (float*)(cursor + NN);   // NN
  int*   rowptr = (int*)(inv + NN);        // NN+1
  int*   bsum   = rowptr + NN + 1;         // 256
  int*   colarr = bsum + 256;              // EE

  // ---- CSR build ----
  hipMemsetAsync(cnt, 0, 2 * NN * sizeof(int), stream);
  k_degree<<<(EE + 255) / 256, 256, 0, stream>>>(ei, cnt);
  k_scan_block<<<SCAN_NB, 256, 0, stream>>>(cnt, rowptr, bsum, inv);
  k_scan_add<<<SCAN_NB, 256, 0, stream>>>(rowptr, bsum);
  k_fill<<<(EE + 255) / 256, 256, 0, stream>>>(ei, rowptr, cursor, colarr);
  k_prep_w<<<(7 * 16384 + CC * 128 + 255) / 256, 256, 0, stream>>>(
      pw1, pw2, swl, swr, cw1, cw2, wt);

  const int MG = (NN + 127) / 128;  // 391
  // h = LN(relu(x@pw1+pb1)@pw2+pb2)   -> hb
  k_mlp<<<MG, 256, 0, stream>>>(x, wt + 0 * 16384, pb1, wt + 1 * 16384, pb2, ing, inb, hb);

  // layer 0
  k_gather_q<<<(NN + 15) / 16, 256, 0, stream>>>(hb, rowptr, colarr, inv, bufA);
  k_sage0<<<MG, 256, 0, stream>>>(
      bufA, hb, wt + 2 * 16384, wt + 4 * 16384, sbl, lng, lnb, hb);

  // layer 1 + classifier
  k_gather_q<<<(NN + 15) / 16, 256, 0, stream>>>(hb, rowptr, colarr, inv, bufA);
  k_sage_cls<<<MG, 256, 0, stream>>>(
      bufA, hb, wt + 3 * 16384, wt + 5 * 16384, sbl + HH, lng + HH, lnb + HH,
      wt + 6 * 16384, cb1, wt + 7 * 16384, cb2, out_h, out_logits);
}

// Round 11
// 166.155 us; speedup vs baseline: 1.3188x; 1.1358x over previous
//
#include <hip/hip_runtime.h>

// GNN encoder: input MLP + LN, 2x SAGEConv(mean) + ReLU + residual + LN, classifier MLP.
// Round 11 (base = round 10): CSR-build cost attack.
//  - hipMemsetAsync(cnt, 400KB) measured 42us as fillBufferAligned -> own k_zero kernel
//  - k_fill was 42us (640K device-scope atomics + line-dirtying scatter): k_degree's
//    atomicAdd return value IS the edge's rank -> store rank[e]; fill becomes atomic-free.
// Dense kernels unchanged: 128 rows/block, swizzled-LDS-staged weights, 2 row-tiles/wave.

namespace {

constexpr int NN = 50000;
constexpr int EE = 640000;
constexpr int HH = 128;
constexpr int CC = 40;
constexpr int SCAN_NB = (NN + 255) / 256;  // 196

typedef unsigned short u16;
typedef __attribute__((ext_vector_type(8))) short s16x8;
typedef __attribute__((ext_vector_type(8))) unsigned short u16x8;
typedef __attribute__((ext_vector_type(4))) float f32x4;

__device__ __forceinline__ float b2f(u16 h) {
  unsigned int u = ((unsigned int)h) << 16;
  return __builtin_bit_cast(float, u);
}
__device__ __forceinline__ u16 f2b(float f) {
  unsigned int u = __builtin_bit_cast(unsigned int, f);
  u += 0x7FFFu + ((u >> 16) & 1u);
  return (u16)(u >> 16);
}

// ---- swizzled LDS tile: row n, 16B-granule k0; slot = k0 ^ (n&15) ----
__device__ __forceinline__ s16x8 ldsw(const u16* base, int n, int k0) {
  return *reinterpret_cast<const s16x8*>(base + n * 128 + (((k0 ^ n) & 15) << 3));
}
__device__ __forceinline__ void stsw(u16* base, int r, int c, u16 v) {
  base[r * 128 + ((((c >> 3) ^ r) & 15) << 3) + (c & 7)] = v;
}
template <int NGRAN>
__device__ __forceinline__ void stage(const u16* __restrict__ src, u16* dst, int tid) {
#pragma unroll
  for (int i = 0; i < (NGRAN + 255) / 256; ++i) {
    const int gi = i * 256 + tid;
    if ((NGRAN & 255) == 0 || gi < NGRAN) {
      const int n = gi >> 4, k0 = gi & 15;
      const u16x8 v = *reinterpret_cast<const u16x8*>(src + gi * 8);
      *reinterpret_cast<u16x8*>(dst + n * 128 + (((k0 ^ n) & 15) << 3)) = v;
    }
  }
}

// ---------------- CSR build ----------------
__global__ void k_zero(int* __restrict__ p) {
  const int i = blockIdx.x * 256 + threadIdx.x;
  if (i < NN) p[i] = 0;
}

// degree histogram; atomic return value = edge's rank among same-dst edges
__global__ void k_degree(const int* __restrict__ ei, int* __restrict__ cnt,
                         int* __restrict__ rank) {
  int e = blockIdx.x * 256 + threadIdx.x;
  if (e < EE) rank[e] = atomicAdd(&cnt[ei[EE + e]], 1);
}

__global__ void k_scan_block(const int* __restrict__ cnt, int* __restrict__ rowptr,
                             int* __restrict__ bsum, float* __restrict__ inv) {
  __shared__ int s[256];
  const int t = threadIdx.x;
  const int i = blockIdx.x * 256 + t;
  const int v = i < NN ? cnt[i] : 0;
  s[t] = v;
  __syncthreads();
  for (int off = 1; off < 256; off <<= 1) {
    int add = t >= off ? s[t - off] : 0;
    __syncthreads();
    s[t] += add;
    __syncthreads();
  }
  if (i < NN) {
    rowptr[i] = s[t] - v;
    inv[i] = v > 0 ? 1.0f / (float)v : 0.0f;
  }
  if (t == 255) bsum[blockIdx.x] = s[255];
}

// merged tops-scan + add: each block scans bsum locally, adds its exclusive prefix
__global__ void k_scan_add(int* __restrict__ rowptr, const int* __restrict__ bsum) {
  __shared__ int s[256];
  const int t = threadIdx.x;
  const int v = t < SCAN_NB ? bsum[t] : 0;
  s[t] = v;
  __syncthreads();
  for (int off = 1; off < 256; off <<= 1) {
    int add = t >= off ? s[t - off] : 0;
    __syncthreads();
    s[t] += add;
    __syncthreads();
  }
  const int boff = blockIdx.x == 0 ? 0 : s[blockIdx.x - 1];
  const int i = blockIdx.x * 256 + t;
  if (i < NN) rowptr[i] += boff;
  if (i == 0) rowptr[NN] = EE;
}

// atomic-free fill: position = rowptr[dst] + rank[e]
__global__ void k_fill(const int* __restrict__ ei, const int* __restrict__ rowptr,
                       const int* __restrict__ rank, int* __restrict__ col) {
  int e = blockIdx.x * 256 + threadIdx.x;
  if (e >= EE) return;
  const int d = ei[EE + e];
  col[rowptr[d] + rank[e]] = ei[e];
}

// transpose+cast all weights into wt slots {pw1,pw2,wl0,wl1,wr0,wr1,cw1,cw2T}
__global__ void k_prep_w(const float* __restrict__ pw1, const float* __restrict__ pw2,
                         const float* __restrict__ swl, const float* __restrict__ swr,
                         const float* __restrict__ cw1, const float* __restrict__ cw2,
                         u16* __restrict__ wt) {
  int flat = blockIdx.x * 256 + threadIdx.x;
  const int SEVEN = 7 * 16384;
  if (flat < SEVEN) {
    int id = flat >> 14;
    int off = flat & 16383;
    int n = off >> 7, k = off & 127;
    const float* s;
    switch (id) {
      case 0: s = pw1; break;
      case 1: s = pw2; break;
      case 2: s = swl; break;
      case 3: s = swl + 16384; break;
      case 4: s = swr; break;
      case 5: s = swr + 16384; break;
      default: s = cw1; break;
    }
    wt[(size_t)id * 16384 + n * 128 + k] = f2b(s[k * 128 + n]);
  } else {
    int off = flat - SEVEN;
    if (off < CC * 128) {
      int n = off >> 7, k = off & 127;
      wt[(size_t)7 * 16384 + n * 128 + k] = f2b(cw2[k * CC + n]);
    }
  }
}

// ---------------- aggregation: quarter-wave per node, 8 edges in flight ----------------
__global__ __launch_bounds__(256) void k_gather_q(
    const u16* __restrict__ hb, const int* __restrict__ rowptr,
    const int* __restrict__ col, const float* __restrict__ inv,
    u16* __restrict__ agg) {
  const int tid = threadIdx.x;
  const int node = blockIdx.x * 16 + (tid >> 4);
  if (node >= NN) return;
  const int ln = tid & 15;
  const int cl = ln * 8;
  const int start = rowptr[node];
  const int end = rowptr[node + 1];
  float a[8] = {0.f, 0.f, 0.f, 0.f, 0.f, 0.f, 0.f, 0.f};
  int i = start;
  for (; i + 8 <= end; i += 8) {
    const int s0 = col[i], s1 = col[i + 1], s2 = col[i + 2], s3 = col[i + 3];
    const int s4 = col[i + 4], s5 = col[i + 5], s6 = col[i + 6], s7 = col[i + 7];
    const u16x8 v0 = *reinterpret_cast<const u16x8*>(&hb[(size_t)s0 * HH + cl]);
    const u16x8 v1 = *reinterpret_cast<const u16x8*>(&hb[(size_t)s1 * HH + cl]);
    const u16x8 v2 = *reinterpret_cast<const u16x8*>(&hb[(size_t)s2 * HH + cl]);
    const u16x8 v3 = *reinterpret_cast<const u16x8*>(&hb[(size_t)s3 * HH + cl]);
    const u16x8 v4 = *reinterpret_cast<const u16x8*>(&hb[(size_t)s4 * HH + cl]);
    const u16x8 v5 = *reinterpret_cast<const u16x8*>(&hb[(size_t)s5 * HH + cl]);
    const u16x8 v6 = *reinterpret_cast<const u16x8*>(&hb[(size_t)s6 * HH + cl]);
    const u16x8 v7 = *reinterpret_cast<const u16x8*>(&hb[(size_t)s7 * HH + cl]);
#pragma unroll
    for (int k = 0; k < 8; ++k)
      a[k] += ((b2f(v0[k]) + b2f(v1[k])) + (b2f(v2[k]) + b2f(v3[k]))) +
              ((b2f(v4[k]) + b2f(v5[k])) + (b2f(v6[k]) + b2f(v7[k])));
  }
  if (i + 4 <= end) {
    const int s0 = col[i], s1 = col[i + 1], s2 = col[i + 2], s3 = col[i + 3];
    const u16x8 v0 = *reinterpret_cast<const u16x8*>(&hb[(size_t)s0 * HH + cl]);
    const u16x8 v1 = *reinterpret_cast<const u16x8*>(&hb[(size_t)s1 * HH + cl]);
    const u16x8 v2 = *reinterpret_cast<const u16x8*>(&hb[(size_t)s2 * HH + cl]);
    const u16x8 v3 = *reinterpret_cast<const u16x8*>(&hb[(size_t)s3 * HH + cl]);
#pragma unroll
    for (int k = 0; k < 8; ++k)
      a[k] += (b2f(v0[k]) + b2f(v1[k])) + (b2f(v2[k]) + b2f(v3[k]));
    i += 4;
  }
  for (; i < end; ++i) {
    const u16x8 v0 = *reinterpret_cast<const u16x8*>(&hb[(size_t)col[i] * HH + cl]);
#pragma unroll
    for (int k = 0; k < 8; ++k) a[k] += b2f(v0[k]);
  }
  const float sc = inv[node];
  u16x8 o;
#pragma unroll
  for (int k = 0; k < 8; ++k) o[k] = f2b(a[k] * sc);
  *reinterpret_cast<u16x8*>(&agg[(size_t)node * HH + cl]) = o;
}

// ---------------- fused input MLP: h = LN(relu(x@pw1+pb1)@pw2+pb2) ----------------
// LDS: [0,16384) = W (WT1 then WT2), [16384,32768) = t1 tile (128x128 swizzled)
__global__ __launch_bounds__(256) void k_mlp(
    const float* __restrict__ x, const u16* __restrict__ WT1,
    const float* __restrict__ pb1, const u16* __restrict__ WT2,
    const float* __restrict__ pb2, const float* __restrict__ lg,
    const float* __restrict__ lb, u16* __restrict__ hb) {
  __shared__ u16 lds[32768];
  u16* wreg = lds;
  u16* t1r = lds + 16384;
  const int tid = threadIdx.x;
  const int wv = tid >> 6, ln = tid & 63;
  const int lrow = ln & 15, kg = ln >> 4;
  const int tbase = blockIdx.x * 128 + wv * 32;
  const int lb0 = wv * 32;
  const int ar0 = min(tbase + lrow, NN - 1);
  const int ar1 = min(tbase + 16 + lrow, NN - 1);

  stage<2048>(WT1, wreg, tid);
  __syncthreads();

  f32x4 acc0[8], acc1[8];
#pragma unroll
  for (int cf = 0; cf < 8; ++cf) {
    acc0[cf] = (f32x4){0.f, 0.f, 0.f, 0.f};
    acc1[cf] = (f32x4){0.f, 0.f, 0.f, 0.f};
  }
#pragma unroll
  for (int ks = 0; ks < 4; ++ks) {
    const float4* p0 = reinterpret_cast<const float4*>(x + (size_t)ar0 * 128 + ks * 32 + kg * 8);
    const float4* p1 = reinterpret_cast<const float4*>(x + (size_t)ar1 * 128 + ks * 32 + kg * 8);
    float4 x0 = p0[0], x1 = p0[1], y0 = p1[0], y1 = p1[1];
    s16x8 a0, a1;
    a0[0] = (short)f2b(x0.x); a0[1] = (short)f2b(x0.y); a0[2] = (short)f2b(x0.z); a0[3] = (short)f2b(x0.w);
    a0[4] = (short)f2b(x1.x); a0[5] = (short)f2b(x1.y); a0[6] = (short)f2b(x1.z); a0[7] = (short)f2b(x1.w);
    a1[0] = (short)f2b(y0.x); a1[1] = (short)f2b(y0.y); a1[2] = (short)f2b(y0.z); a1[3] = (short)f2b(y0.w);
    a1[4] = (short)f2b(y1.x); a1[5] = (short)f2b(y1.y); a1[6] = (short)f2b(y1.z); a1[7] = (short)f2b(y1.w);
#pragma unroll
    for (int cf = 0; cf < 8; ++cf) {
      const s16x8 bf = ldsw(wreg, cf * 16 + lrow, ks * 4 + kg);
      acc0[cf] = __builtin_amdgcn_mfma_f32_16x16x32_bf16(a0, bf, acc0[cf], 0, 0, 0);
      acc1[cf] = __builtin_amdgcn_mfma_f32_16x16x32_bf16(a1, bf, acc1[cf], 0, 0, 0);
    }
  }
  {
    float bb[8];
#pragma unroll
    for (int cf = 0; cf < 8; ++cf) bb[cf] = pb1[cf * 16 + lrow];
#pragma unroll
    for (int t = 0; t < 2; ++t)
#pragma unroll
      for (int j = 0; j < 4; ++j) {
        const int lr = lb0 + t * 16 + kg * 4 + j;
#pragma unroll
        for (int cf = 0; cf < 8; ++cf)
          stsw(t1r, lr, cf * 16 + lrow, f2b(fmaxf((t ? acc1[cf][j] : acc0[cf][j]) + bb[cf], 0.0f)));
      }
  }
  __syncthreads();
  stage<2048>(WT2, wreg, tid);
  __syncthreads();

  f32x4 c0[8], c1[8];
#pragma unroll
  for (int cf = 0; cf < 8; ++cf) {
    c0[cf] = (f32x4){0.f, 0.f, 0.f, 0.f};
    c1[cf] = (f32x4){0.f, 0.f, 0.f, 0.f};
  }
#pragma unroll
  for (int ks = 0; ks < 4; ++ks) {
    const s16x8 a0 = ldsw(t1r, lb0 + lrow, ks * 4 + kg);
    const s16x8 a1 = ldsw(t1r, lb0 + 16 + lrow, ks * 4 + kg);
#pragma unroll
    for (int cf = 0; cf < 8; ++cf) {
      const s16x8 bf = ldsw(wreg, cf * 16 + lrow, ks * 4 + kg);
      c0[cf] = __builtin_amdgcn_mfma_f32_16x16x32_bf16(a0, bf, c0[cf], 0, 0, 0);
      c1[cf] = __builtin_amdgcn_mfma_f32_16x16x32_bf16(a1, bf, c1[cf], 0, 0, 0);
    }
  }

  float bb[8], gm[8], gb[8];
#pragma unroll
  for (int cf = 0; cf < 8; ++cf) {
    const int c = cf * 16 + lrow;
    bb[cf] = pb2[c];
    gm[cf] = lg[c];
    gb[cf] = lb[c];
  }
#pragma unroll
  for (int t = 0; t < 2; ++t)
#pragma unroll
    for (int j = 0; j < 4; ++j) {
      const int r = tbase + t * 16 + kg * 4 + j;
      float v[8];
#pragma unroll
      for (int cf = 0; cf < 8; ++cf) v[cf] = (t ? c1[cf][j] : c0[cf][j]) + bb[cf];
      float s = 0.f;
#pragma unroll
      for (int cf = 0; cf < 8; ++cf) s += v[cf];
      s += __shfl_xor(s, 1); s += __shfl_xor(s, 2);
      s += __shfl_xor(s, 4); s += __shfl_xor(s, 8);
      const float mu = s * (1.0f / 128);
      float q = 0.f;
#pragma unroll
      for (int cf = 0; cf < 8; ++cf) { const float d = v[cf] - mu; q += d * d; }
      q += __shfl_xor(q, 1); q += __shfl_xor(q, 2);
      q += __shfl_xor(q, 4); q += __shfl_xor(q, 8);
      const float istd = rsqrtf(q * (1.0f / 128) + 1e-5f);
      if (r < NN) {
#pragma unroll
        for (int cf = 0; cf < 8; ++cf)
          hb[(size_t)r * 128 + cf * 16 + lrow] = f2b((v[cf] - mu) * istd * gm[cf] + gb[cf]);
      }
    }
}

// ---------------- SAGE layer 0: h' = LN(h + relu(agg@WL + bl + h@WR)) -> hb ----------------
__global__ __launch_bounds__(256) void k_sage0(
    const u16* __restrict__ agg, const u16* __restrict__ hb,
    const u16* __restrict__ WTl, const u16* __restrict__ WTr,
    const float* __restrict__ bl, const float* __restrict__ lg,
    const float* __restrict__ lb, u16* __restrict__ hb_out) {
  __shared__ u16 lds[32768];
  u16* wl = lds;
  u16* wr = lds + 16384;
  const int tid = threadIdx.x;
  const int wv = tid >> 6, ln = tid & 63;
  const int lrow = ln & 15, kg = ln >> 4;
  const int tbase = blockIdx.x * 128 + wv * 32;
  const int ar0 = min(tbase + lrow, NN - 1);
  const int ar1 = min(tbase + 16 + lrow, NN - 1);

  stage<2048>(WTl, wl, tid);
  stage<2048>(WTr, wr, tid);
  __syncthreads();

  f32x4 acc0[8], acc1[8];
#pragma unroll
  for (int cf = 0; cf < 8; ++cf) {
    acc0[cf] = (f32x4){0.f, 0.f, 0.f, 0.f};
    acc1[cf] = (f32x4){0.f, 0.f, 0.f, 0.f};
  }
#pragma unroll
  for (int ks = 0; ks < 4; ++ks) {
    const s16x8 g0 = *reinterpret_cast<const s16x8*>(agg + (size_t)ar0 * 128 + ks * 32 + kg * 8);
    const s16x8 g1 = *reinterpret_cast<const s16x8*>(agg + (size_t)ar1 * 128 + ks * 32 + kg * 8);
    const s16x8 h0 = *reinterpret_cast<const s16x8*>(hb + (size_t)ar0 * 128 + ks * 32 + kg * 8);
    const s16x8 h1 = *reinterpret_cast<const s16x8*>(hb + (size_t)ar1 * 128 + ks * 32 + kg * 8);
#pragma unroll
    for (int cf = 0; cf < 8; ++cf) {
      const s16x8 bwl = ldsw(wl, cf * 16 + lrow, ks * 4 + kg);
      const s16x8 bwr = ldsw(wr, cf * 16 + lrow, ks * 4 + kg);
      acc0[cf] = __builtin_amdgcn_mfma_f32_16x16x32_bf16(g0, bwl, acc0[cf], 0, 0, 0);
      acc0[cf] = __builtin_amdgcn_mfma_f32_16x16x32_bf16(h0, bwr, acc0[cf], 0, 0, 0);
      acc1[cf] = __builtin_amdgcn_mfma_f32_16x16x32_bf16(g1, bwl, acc1[cf], 0, 0, 0);
      acc1[cf] = __builtin_amdgcn_mfma_f32_16x16x32_bf16(h1, bwr, acc1[cf], 0, 0, 0);
    }
  }

  float bb[8], gm[8], gb[8];
#pragma unroll
  for (int cf = 0; cf < 8; ++cf) {
    const int c = cf * 16 + lrow;
    bb[cf] = bl[c];
    gm[cf] = lg[c];
    gb[cf] = lb[c];
  }
#pragma unroll
  for (int t = 0; t < 2; ++t)
#pragma unroll
    for (int j = 0; j < 4; ++j) {
      const int r = tbase + t * 16 + kg * 4 + j;
      const int rs = r < NN ? r : NN - 1;
      float v[8];
#pragma unroll
      for (int cf = 0; cf < 8; ++cf) {
        const int c = cf * 16 + lrow;
        v[cf] = b2f(hb[(size_t)rs * 128 + c]) +
                fmaxf((t ? acc1[cf][j] : acc0[cf][j]) + bb[cf], 0.0f);
      }
      float s = 0.f;
#pragma unroll
      for (int cf = 0; cf < 8; ++cf) s += v[cf];
      s += __shfl_xor(s, 1); s += __shfl_xor(s, 2);
      s += __shfl_xor(s, 4); s += __shfl_xor(s, 8);
      const float mu = s * (1.0f / 128);
      float q = 0.f;
#pragma unroll
      for (int cf = 0; cf < 8; ++cf) { const float d = v[cf] - mu; q += d * d; }
      q += __shfl_xor(q, 1); q += __shfl_xor(q, 2);
      q += __shfl_xor(q, 4); q += __shfl_xor(q, 8);
      const float istd = rsqrtf(q * (1.0f / 128) + 1e-5f);
      if (r < NN) {
#pragma unroll
        for (int cf = 0; cf < 8; ++cf)
          hb_out[(size_t)r * 128 + cf * 16 + lrow] = f2b((v[cf] - mu) * istd * gm[cf] + gb[cf]);
      }
    }
}

// ---------------- SAGE layer 1 + classifier fused ----------------
// LDS: [0,16384)=WTl -> th tile; [16384,32768)=WTr -> Wc1; [32768,37888)=Wc2
__global__ __launch_bounds__(256) void k_sage_cls(
    const u16* __restrict__ agg, const u16* __restrict__ hb,
    const u16* __restrict__ WTl, const u16* __restrict__ WTr,
    const float* __restrict__ bl, const float* __restrict__ lg,
    const float* __restrict__ lb,
    const u16* __restrict__ Wc1, const float* __restrict__ cb1,
    const u16* __restrict__ Wc2, const float* __restrict__ cb2,
    float* __restrict__ out_h, float* __restrict__ logits) {
  __shared__ u16 lds[37888];
  u16* wl = lds;          // phase A: WTl ; phase B: th tile (128x128)
  u16* wr = lds + 16384;  // phase A: WTr ; phase B: Wc1
  u16* w2 = lds + 32768;  // Wc2 (40x128)
  const int tid = threadIdx.x;
  const int wv = tid >> 6, ln = tid & 63;
  const int lrow = ln & 15, kg = ln >> 4;
  const int tbase = blockIdx.x * 128 + wv * 32;
  const int lb0 = wv * 32;
  const int ar0 = min(tbase + lrow, NN - 1);
  const int ar1 = min(tbase + 16 + lrow, NN - 1);

  stage<2048>(WTl, wl, tid);
  stage<2048>(WTr, wr, tid);
  stage<640>(Wc2, w2, tid);
  __syncthreads();

  f32x4 acc0[8], acc1[8];
#pragma unroll
  for (int cf = 0; cf < 8; ++cf) {
    acc0[cf] = (f32x4){0.f, 0.f, 0.f, 0.f};
    acc1[cf] = (f32x4){0.f, 0.f, 0.f, 0.f};
  }
#pragma unroll
  for (int ks = 0; ks < 4; ++ks) {
    const s16x8 g0 = *reinterpret_cast<const s16x8*>(agg + (size_t)ar0 * 128 + ks * 32 + kg * 8);
    const s16x8 g1 = *reinterpret_cast<const s16x8*>(agg + (size_t)ar1 * 128 + ks * 32 + kg * 8);
    const s16x8 h0 = *reinterpret_cast<const s16x8*>(hb + (size_t)ar0 * 128 + ks * 32 + kg * 8);
    const s16x8 h1 = *reinterpret_cast<const s16x8*>(hb + (size_t)ar1 * 128 + ks * 32 + kg * 8);
#pragma unroll
    for (int cf = 0; cf < 8; ++cf) {
      const s16x8 bwl = ldsw(wl, cf * 16 + lrow, ks * 4 + kg);
      const s16x8 bwr = ldsw(wr, cf * 16 + lrow, ks * 4 + kg);
      acc0[cf] = __builtin_amdgcn_mfma_f32_16x16x32_bf16(g0, bwl, acc0[cf], 0, 0, 0);
      acc0[cf] = __builtin_amdgcn_mfma_f32_16x16x32_bf16(h0, bwr, acc0[cf], 0, 0, 0);
      acc1[cf] = __builtin_amdgcn_mfma_f32_16x16x32_bf16(g1, bwl, acc1[cf], 0, 0, 0);
      acc1[cf] = __builtin_amdgcn_mfma_f32_16x16x32_bf16(h1, bwr, acc1[cf], 0, 0, 0);
    }
  }
  __syncthreads();  // all waves done reading WTl/WTr

  {
    float bb[8], gm[8], gb[8];
#pragma unroll
    for (int cf = 0; cf < 8; ++cf) {
      const int c = cf * 16 + lrow;
      bb[cf] = bl[c];
      gm[cf] = lg[c];
      gb[cf] = lb[c];
    }
#pragma unroll
    for (int t = 0; t < 2; ++t)
#pragma unroll
      for (int j = 0; j < 4; ++j) {
        const int r = tbase + t * 16 + kg * 4 + j;
        const int rs = r < NN ? r : NN - 1;
        const int lr = lb0 + t * 16 + kg * 4 + j;
        float v[8];
#pragma unroll
        for (int cf = 0; cf < 8; ++cf) {
          const int c = cf * 16 + lrow;
          v[cf] = b2f(hb[(size_t)rs * 128 + c]) +
                  fmaxf((t ? acc1[cf][j] : acc0[cf][j]) + bb[cf], 0.0f);
        }
        float s = 0.f;
#pragma unroll
        for (int cf = 0; cf < 8; ++cf) s += v[cf];
        s += __shfl_xor(s, 1); s += __shfl_xor(s, 2);
        s += __shfl_xor(s, 4); s += __shfl_xor(s, 8);
        const float mu = s * (1.0f / 128);
        float q = 0.f;
#pragma unroll
        for (int cf = 0; cf < 8; ++cf) { const float d = v[cf] - mu; q += d * d; }
        q += __shfl_xor(q, 1); q += __shfl_xor(q, 2);
        q += __shfl_xor(q, 4); q += __shfl_xor(q, 8);
        const float istd = rsqrtf(q * (1.0f / 128) + 1e-5f);
#pragma unroll
        for (int cf = 0; cf < 8; ++cf) {
          const int c = cf * 16 + lrow;
          const float o = (v[cf] - mu) * istd * gm[cf] + gb[cf];
          stsw(wl, lr, c, f2b(o));
          if (r < NN) out_h[(size_t)r * 128 + c] = o;
        }
      }
  }
  stage<2048>(Wc1, wr, tid);  // Wc1 over WTr (all reads done at barrier above)
  __syncthreads();

  // classifier: per wave, its own two 16-row th tiles
  float cb1v[8];
#pragma unroll
  for (int cf = 0; cf < 8; ++cf) cb1v[cf] = cb1[cf * 16 + lrow];

#pragma unroll
  for (int t = 0; t < 2; ++t) {
    const int rb = lb0 + t * 16;
    f32x4 a3[8];
#pragma unroll
    for (int cf = 0; cf < 8; ++cf) a3[cf] = (f32x4){0.f, 0.f, 0.f, 0.f};
#pragma unroll
    for (int ks = 0; ks < 4; ++ks) {
      const s16x8 a = ldsw(wl, rb + lrow, ks * 4 + kg);
#pragma unroll
      for (int cf = 0; cf < 8; ++cf) {
        const s16x8 bf = ldsw(wr, cf * 16 + lrow, ks * 4 + kg);
        a3[cf] = __builtin_amdgcn_mfma_f32_16x16x32_bf16(a, bf, a3[cf], 0, 0, 0);
      }
    }
    // t3 overwrites this wave's own th rows
#pragma unroll
    for (int j = 0; j < 4; ++j)
#pragma unroll
      for (int cf = 0; cf < 8; ++cf)
        stsw(wl, rb + kg * 4 + j, cf * 16 + lrow, f2b(fmaxf(a3[cf][j] + cb1v[cf], 0.0f)));

    f32x4 a2[3];
#pragma unroll
    for (int cf = 0; cf < 3; ++cf) a2[cf] = (f32x4){0.f, 0.f, 0.f, 0.f};
#pragma unroll
    for (int ks = 0; ks < 4; ++ks) {
      const s16x8 a = ldsw(wl, rb + lrow, ks * 4 + kg);
#pragma unroll
      for (int cf = 0; cf < 3; ++cf) {
        const int bn = min(cf * 16 + lrow, CC - 1);
        const s16x8 bf = ldsw(w2, bn, ks * 4 + kg);
        a2[cf] = __builtin_amdgcn_mfma_f32_16x16x32_bf16(a, bf, a2[cf], 0, 0, 0);
      }
    }
#pragma unroll
    for (int j = 0; j < 4; ++j) {
      const int r = tbase + t * 16 + kg * 4 + j;
      if (r < NN) {
#pragma unroll
        for (int cf = 0; cf < 3; ++cf) {
          const int c = cf * 16 + lrow;
          if (c < CC) logits[(size_t)r * CC + c] = a2[cf][j] + cb2[c];
        }
      }
    }
  }
}

}  // namespace

extern "C" void kernel_launch(void* const* d_in, const int* in_sizes, int n_in,
                              void* d_out, int out_size, void* d_ws, size_t ws_size,
                              hipStream_t stream) {
  (void)in_sizes; (void)n_in; (void)out_size; (void)ws_size;
  const float* x   = (const float*)d_in[0];
  const int*   ei  = (const int*)d_in[1];
  const float* pw1 = (const float*)d_in[2];
  const float* pb1 = (const float*)d_in[3];
  const float* pw2 = (const float*)d_in[4];
  const float* pb2 = (const float*)d_in[5];
  const float* ing = (const float*)d_in[6];
  const float* inb = (const float*)d_in[7];
  const float* swl = (const float*)d_in[8];
  const float* sbl = (const float*)d_in[9];
  const float* swr = (const float*)d_in[10];
  const float* lng = (const float*)d_in[11];
  const float* lnb = (const float*)d_in[12];
  const float* cw1 = (const float*)d_in[13];
  const float* cb1 = (const float*)d_in[14];
  const float* cw2 = (const float*)d_in[15];
  const float* cb2 = (const float*)d_in[16];

  float* out_logits = (float*)d_out;
  float* out_h = out_logits + (size_t)NN * CC;

  const size_t NNH = (size_t)NN * HH;
  u16*   hb   = (u16*)d_ws;                // 12.8 MB
  u16*   bufA = hb + NNH;                  // 12.8 MB (agg)
  u16*   wt   = bufA + NNH;                // 256 KB
  int*   cnt    = (int*)(wt + 8 * 16384);  // NN
  float* inv    = (float*)(cnt + NN);      // NN
  int*   rowptr = (int*)(inv + NN);        // NN+1
  int*   bsum   = rowptr + NN + 1;         // 256
  int*   colarr = bsum + 256;              // EE
  int*   rankar = colarr + EE;             // EE

  // ---- CSR build (atomic-rank fill; no runtime memset) ----
  k_zero<<<SCAN_NB, 256, 0, stream>>>(cnt);
  k_degree<<<(EE + 255) / 256, 256, 0, stream>>>(ei, cnt, rankar);
  k_scan_block<<<SCAN_NB, 256, 0, stream>>>(cnt, rowptr, bsum, inv);
  k_scan_add<<<SCAN_NB, 256, 0, stream>>>(rowptr, bsum);
  k_fill<<<(EE + 255) / 256, 256, 0, stream>>>(ei, rowptr, rankar, colarr);
  k_prep_w<<<(7 * 16384 + CC * 128 + 255) / 256, 256, 0, stream>>>(
      pw1, pw2, swl, swr, cw1, cw2, wt);

  const int MG = (NN + 127) / 128;  // 391
  // h = LN(relu(x@pw1+pb1)@pw2+pb2)   -> hb
  k_mlp<<<MG, 256, 0, stream>>>(x, wt + 0 * 16384, pb1, wt + 1 * 16384, pb2, ing, inb, hb);

  // layer 0
  k_gather_q<<<(NN + 15) / 16, 256, 0, stream>>>(hb, rowptr, colarr, inv, bufA);
  k_sage0<<<MG, 256, 0, stream>>>(
      bufA, hb, wt + 2 * 16384, wt + 4 * 16384, sbl, lng, lnb, hb);

  // layer 1 + classifier
  k_gather_q<<<(NN + 15) / 16, 256, 0, stream>>>(hb, rowptr, colarr, inv, bufA);
  k_sage_cls<<<MG, 256, 0, stream>>>(
      bufA, hb, wt + 3 * 16384, wt + 5 * 16384, sbl + HH, lng + HH, lnb + HH,
      wt + 6 * 16384, cb1, wt + 7 * 16384, cb2, out_h, out_logits);
}

// Round 12
// 153.592 us; speedup vs baseline: 1.4267x; 1.0818x over previous
//
#include <hip/hip_runtime.h>

// GNN encoder: input MLP + LN, 2x SAGEConv(mean) + ReLU + residual + LN, classifier MLP.
// Round 12 (base = round 11): dispatch-graph compaction.
//  - k_pre: cnt-zero + weight transpose merged (independent prelude work)
//  - k_mlp_deg: degree+rank histogram blocks ride inside the MLP dispatch
//    (independent work; degree hides under mlp's compute)
//  - CSR scan/fill, gathers, sage kernels unchanged from round 11.

namespace {

constexpr int NN = 50000;
constexpr int EE = 640000;
constexpr int HH = 128;
constexpr int CC = 40;
constexpr int SCAN_NB = (NN + 255) / 256;  // 196
constexpr int MG = (NN + 127) / 128;       // 391 (mlp blocks)
constexpr int DEGB = (EE + 255) / 256;     // 2500 (degree blocks)

typedef unsigned short u16;
typedef __attribute__((ext_vector_type(8))) short s16x8;
typedef __attribute__((ext_vector_type(8))) unsigned short u16x8;
typedef __attribute__((ext_vector_type(4))) float f32x4;

__device__ __forceinline__ float b2f(u16 h) {
  unsigned int u = ((unsigned int)h) << 16;
  return __builtin_bit_cast(float, u);
}
__device__ __forceinline__ u16 f2b(float f) {
  unsigned int u = __builtin_bit_cast(unsigned int, f);
  u += 0x7FFFu + ((u >> 16) & 1u);
  return (u16)(u >> 16);
}

// ---- swizzled LDS tile: row n, 16B-granule k0; slot = k0 ^ (n&15) ----
__device__ __forceinline__ s16x8 ldsw(const u16* base, int n, int k0) {
  return *reinterpret_cast<const s16x8*>(base + n * 128 + (((k0 ^ n) & 15) << 3));
}
__device__ __forceinline__ void stsw(u16* base, int r, int c, u16 v) {
  base[r * 128 + ((((c >> 3) ^ r) & 15) << 3) + (c & 7)] = v;
}
template <int NGRAN>
__device__ __forceinline__ void stage(const u16* __restrict__ src, u16* dst, int tid) {
#pragma unroll
  for (int i = 0; i < (NGRAN + 255) / 256; ++i) {
    const int gi = i * 256 + tid;
    if ((NGRAN & 255) == 0 || gi < NGRAN) {
      const int n = gi >> 4, k0 = gi & 15;
      const u16x8 v = *reinterpret_cast<const u16x8*>(src + gi * 8);
      *reinterpret_cast<u16x8*>(dst + n * 128 + (((k0 ^ n) & 15) << 3)) = v;
    }
  }
}

// ---------------- prelude: weight transpose+cast AND cnt zero (merged) ----------------
__global__ void k_pre(const float* __restrict__ pw1, const float* __restrict__ pw2,
                      const float* __restrict__ swl, const float* __restrict__ swr,
                      const float* __restrict__ cw1, const float* __restrict__ cw2,
                      u16* __restrict__ wt, int* __restrict__ cnt) {
  int flat = blockIdx.x * 256 + threadIdx.x;
  const int SEVEN = 7 * 16384;
  const int WDOM = SEVEN + CC * 128;
  if (flat < SEVEN) {
    int id = flat >> 14;
    int off = flat & 16383;
    int n = off >> 7, k = off & 127;
    const float* s;
    switch (id) {
      case 0: s = pw1; break;
      case 1: s = pw2; break;
      case 2: s = swl; break;
      case 3: s = swl + 16384; break;
      case 4: s = swr; break;
      case 5: s = swr + 16384; break;
      default: s = cw1; break;
    }
    wt[(size_t)id * 16384 + n * 128 + k] = f2b(s[k * 128 + n]);
  } else if (flat < WDOM) {
    int off = flat - SEVEN;
    int n = off >> 7, k = off & 127;
    wt[(size_t)7 * 16384 + n * 128 + k] = f2b(cw2[k * CC + n]);
  } else {
    int i = flat - WDOM;
    if (i < NN) cnt[i] = 0;
  }
}

// ---------------- CSR scan / fill ----------------
__global__ void k_scan_block(const int* __restrict__ cnt, int* __restrict__ rowptr,
                             int* __restrict__ bsum, float* __restrict__ inv) {
  __shared__ int s[256];
  const int t = threadIdx.x;
  const int i = blockIdx.x * 256 + t;
  const int v = i < NN ? cnt[i] : 0;
  s[t] = v;
  __syncthreads();
  for (int off = 1; off < 256; off <<= 1) {
    int add = t >= off ? s[t - off] : 0;
    __syncthreads();
    s[t] += add;
    __syncthreads();
  }
  if (i < NN) {
    rowptr[i] = s[t] - v;
    inv[i] = v > 0 ? 1.0f / (float)v : 0.0f;
  }
  if (t == 255) bsum[blockIdx.x] = s[255];
}

__global__ void k_scan_add(int* __restrict__ rowptr, const int* __restrict__ bsum) {
  __shared__ int s[256];
  const int t = threadIdx.x;
  const int v = t < SCAN_NB ? bsum[t] : 0;
  s[t] = v;
  __syncthreads();
  for (int off = 1; off < 256; off <<= 1) {
    int add = t >= off ? s[t - off] : 0;
    __syncthreads();
    s[t] += add;
    __syncthreads();
  }
  const int boff = blockIdx.x == 0 ? 0 : s[blockIdx.x - 1];
  const int i = blockIdx.x * 256 + t;
  if (i < NN) rowptr[i] += boff;
  if (i == 0) rowptr[NN] = EE;
}

// atomic-free fill: position = rowptr[dst] + rank[e]
__global__ void k_fill(const int* __restrict__ ei, const int* __restrict__ rowptr,
                       const int* __restrict__ rank, int* __restrict__ col) {
  int e = blockIdx.x * 256 + threadIdx.x;
  if (e >= EE) return;
  const int d = ei[EE + e];
  col[rowptr[d] + rank[e]] = ei[e];
}

// ---------------- aggregation: quarter-wave per node, 8 edges in flight ----------------
__global__ __launch_bounds__(256) void k_gather_q(
    const u16* __restrict__ hb, const int* __restrict__ rowptr,
    const int* __restrict__ col, const float* __restrict__ inv,
    u16* __restrict__ agg) {
  const int tid = threadIdx.x;
  const int node = blockIdx.x * 16 + (tid >> 4);
  if (node >= NN) return;
  const int ln = tid & 15;
  const int cl = ln * 8;
  const int start = rowptr[node];
  const int end = rowptr[node + 1];
  float a[8] = {0.f, 0.f, 0.f, 0.f, 0.f, 0.f, 0.f, 0.f};
  int i = start;
  for (; i + 8 <= end; i += 8) {
    const int s0 = col[i], s1 = col[i + 1], s2 = col[i + 2], s3 = col[i + 3];
    const int s4 = col[i + 4], s5 = col[i + 5], s6 = col[i + 6], s7 = col[i + 7];
    const u16x8 v0 = *reinterpret_cast<const u16x8*>(&hb[(size_t)s0 * HH + cl]);
    const u16x8 v1 = *reinterpret_cast<const u16x8*>(&hb[(size_t)s1 * HH + cl]);
    const u16x8 v2 = *reinterpret_cast<const u16x8*>(&hb[(size_t)s2 * HH + cl]);
    const u16x8 v3 = *reinterpret_cast<const u16x8*>(&hb[(size_t)s3 * HH + cl]);
    const u16x8 v4 = *reinterpret_cast<const u16x8*>(&hb[(size_t)s4 * HH + cl]);
    const u16x8 v5 = *reinterpret_cast<const u16x8*>(&hb[(size_t)s5 * HH + cl]);
    const u16x8 v6 = *reinterpret_cast<const u16x8*>(&hb[(size_t)s6 * HH + cl]);
    const u16x8 v7 = *reinterpret_cast<const u16x8*>(&hb[(size_t)s7 * HH + cl]);
#pragma unroll
    for (int k = 0; k < 8; ++k)
      a[k] += ((b2f(v0[k]) + b2f(v1[k])) + (b2f(v2[k]) + b2f(v3[k]))) +
              ((b2f(v4[k]) + b2f(v5[k])) + (b2f(v6[k]) + b2f(v7[k])));
  }
  if (i + 4 <= end) {
    const int s0 = col[i], s1 = col[i + 1], s2 = col[i + 2], s3 = col[i + 3];
    const u16x8 v0 = *reinterpret_cast<const u16x8*>(&hb[(size_t)s0 * HH + cl]);
    const u16x8 v1 = *reinterpret_cast<const u16x8*>(&hb[(size_t)s1 * HH + cl]);
    const u16x8 v2 = *reinterpret_cast<const u16x8*>(&hb[(size_t)s2 * HH + cl]);
    const u16x8 v3 = *reinterpret_cast<const u16x8*>(&hb[(size_t)s3 * HH + cl]);
#pragma unroll
    for (int k = 0; k < 8; ++k)
      a[k] += (b2f(v0[k]) + b2f(v1[k])) + (b2f(v2[k]) + b2f(v3[k]));
    i += 4;
  }
  for (; i < end; ++i) {
    const u16x8 v0 = *reinterpret_cast<const u16x8*>(&hb[(size_t)col[i] * HH + cl]);
#pragma unroll
    for (int k = 0; k < 8; ++k) a[k] += b2f(v0[k]);
  }
  const float sc = inv[node];
  u16x8 o;
#pragma unroll
  for (int k = 0; k < 8; ++k) o[k] = f2b(a[k] * sc);
  *reinterpret_cast<u16x8*>(&agg[(size_t)node * HH + cl]) = o;
}

// ---------------- fused input MLP + ridden degree histogram ----------------
// blocks [0,MG): h = LN(relu(x@pw1+pb1)@pw2+pb2) -> hb
// blocks [MG,MG+DEGB): rank[e] = atomicAdd(&cnt[dst[e]], 1)   (independent work)
__global__ __launch_bounds__(256) void k_mlp_deg(
    const float* __restrict__ x, const u16* __restrict__ WT1,
    const float* __restrict__ pb1, const u16* __restrict__ WT2,
    const float* __restrict__ pb2, const float* __restrict__ lg,
    const float* __restrict__ lb, u16* __restrict__ hb,
    const int* __restrict__ ei, int* __restrict__ cnt, int* __restrict__ rank) {
  __shared__ u16 lds[32768];
  if (blockIdx.x >= MG) {
    const int e = (blockIdx.x - MG) * 256 + threadIdx.x;
    if (e < EE) rank[e] = atomicAdd(&cnt[ei[EE + e]], 1);
    return;
  }
  u16* wreg = lds;
  u16* t1r = lds + 16384;
  const int tid = threadIdx.x;
  const int wv = tid >> 6, ln = tid & 63;
  const int lrow = ln & 15, kg = ln >> 4;
  const int tbase = blockIdx.x * 128 + wv * 32;
  const int lb0 = wv * 32;
  const int ar0 = min(tbase + lrow, NN - 1);
  const int ar1 = min(tbase + 16 + lrow, NN - 1);

  stage<2048>(WT1, wreg, tid);
  __syncthreads();

  f32x4 acc0[8], acc1[8];
#pragma unroll
  for (int cf = 0; cf < 8; ++cf) {
    acc0[cf] = (f32x4){0.f, 0.f, 0.f, 0.f};
    acc1[cf] = (f32x4){0.f, 0.f, 0.f, 0.f};
  }
#pragma unroll
  for (int ks = 0; ks < 4; ++ks) {
    const float4* p0 = reinterpret_cast<const float4*>(x + (size_t)ar0 * 128 + ks * 32 + kg * 8);
    const float4* p1 = reinterpret_cast<const float4*>(x + (size_t)ar1 * 128 + ks * 32 + kg * 8);
    float4 x0 = p0[0], x1 = p0[1], y0 = p1[0], y1 = p1[1];
    s16x8 a0, a1;
    a0[0] = (short)f2b(x0.x); a0[1] = (short)f2b(x0.y); a0[2] = (short)f2b(x0.z); a0[3] = (short)f2b(x0.w);
    a0[4] = (short)f2b(x1.x); a0[5] = (short)f2b(x1.y); a0[6] = (short)f2b(x1.z); a0[7] = (short)f2b(x1.w);
    a1[0] = (short)f2b(y0.x); a1[1] = (short)f2b(y0.y); a1[2] = (short)f2b(y0.z); a1[3] = (short)f2b(y0.w);
    a1[4] = (short)f2b(y1.x); a1[5] = (short)f2b(y1.y); a1[6] = (short)f2b(y1.z); a1[7] = (short)f2b(y1.w);
#pragma unroll
    for (int cf = 0; cf < 8; ++cf) {
      const s16x8 bf = ldsw(wreg, cf * 16 + lrow, ks * 4 + kg);
      acc0[cf] = __builtin_amdgcn_mfma_f32_16x16x32_bf16(a0, bf, acc0[cf], 0, 0, 0);
      acc1[cf] = __builtin_amdgcn_mfma_f32_16x16x32_bf16(a1, bf, acc1[cf], 0, 0, 0);
    }
  }
  {
    float bb[8];
#pragma unroll
    for (int cf = 0; cf < 8; ++cf) bb[cf] = pb1[cf * 16 + lrow];
#pragma unroll
    for (int t = 0; t < 2; ++t)
#pragma unroll
      for (int j = 0; j < 4; ++j) {
        const int lr = lb0 + t * 16 + kg * 4 + j;
#pragma unroll
        for (int cf = 0; cf < 8; ++cf)
          stsw(t1r, lr, cf * 16 + lrow, f2b(fmaxf((t ? acc1[cf][j] : acc0[cf][j]) + bb[cf], 0.0f)));
      }
  }
  __syncthreads();
  stage<2048>(WT2, wreg, tid);
  __syncthreads();

  f32x4 c0[8], c1[8];
#pragma unroll
  for (int cf = 0; cf < 8; ++cf) {
    c0[cf] = (f32x4){0.f, 0.f, 0.f, 0.f};
    c1[cf] = (f32x4){0.f, 0.f, 0.f, 0.f};
  }
#pragma unroll
  for (int ks = 0; ks < 4; ++ks) {
    const s16x8 a0 = ldsw(t1r, lb0 + lrow, ks * 4 + kg);
    const s16x8 a1 = ldsw(t1r, lb0 + 16 + lrow, ks * 4 + kg);
#pragma unroll
    for (int cf = 0; cf < 8; ++cf) {
      const s16x8 bf = ldsw(wreg, cf * 16 + lrow, ks * 4 + kg);
      c0[cf] = __builtin_amdgcn_mfma_f32_16x16x32_bf16(a0, bf, c0[cf], 0, 0, 0);
      c1[cf] = __builtin_amdgcn_mfma_f32_16x16x32_bf16(a1, bf, c1[cf], 0, 0, 0);
    }
  }

  float bb[8], gm[8], gb[8];
#pragma unroll
  for (int cf = 0; cf < 8; ++cf) {
    const int c = cf * 16 + lrow;
    bb[cf] = pb2[c];
    gm[cf] = lg[c];
    gb[cf] = lb[c];
  }
#pragma unroll
  for (int t = 0; t < 2; ++t)
#pragma unroll
    for (int j = 0; j < 4; ++j) {
      const int r = tbase + t * 16 + kg * 4 + j;
      float v[8];
#pragma unroll
      for (int cf = 0; cf < 8; ++cf) v[cf] = (t ? c1[cf][j] : c0[cf][j]) + bb[cf];
      float s = 0.f;
#pragma unroll
      for (int cf = 0; cf < 8; ++cf) s += v[cf];
      s += __shfl_xor(s, 1); s += __shfl_xor(s, 2);
      s += __shfl_xor(s, 4); s += __shfl_xor(s, 8);
      const float mu = s * (1.0f / 128);
      float q = 0.f;
#pragma unroll
      for (int cf = 0; cf < 8; ++cf) { const float d = v[cf] - mu; q += d * d; }
      q += __shfl_xor(q, 1); q += __shfl_xor(q, 2);
      q += __shfl_xor(q, 4); q += __shfl_xor(q, 8);
      const float istd = rsqrtf(q * (1.0f / 128) + 1e-5f);
      if (r < NN) {
#pragma unroll
        for (int cf = 0; cf < 8; ++cf)
          hb[(size_t)r * 128 + cf * 16 + lrow] = f2b((v[cf] - mu) * istd * gm[cf] + gb[cf]);
      }
    }
}

// ---------------- SAGE layer 0: h' = LN(h + relu(agg@WL + bl + h@WR)) -> hb ----------------
__global__ __launch_bounds__(256) void k_sage0(
    const u16* __restrict__ agg, const u16* __restrict__ hb,
    const u16* __restrict__ WTl, const u16* __restrict__ WTr,
    const float* __restrict__ bl, const float* __restrict__ lg,
    const float* __restrict__ lb, u16* __restrict__ hb_out) {
  __shared__ u16 lds[32768];
  u16* wl = lds;
  u16* wr = lds + 16384;
  const int tid = threadIdx.x;
  const int wv = tid >> 6, ln = tid & 63;
  const int lrow = ln & 15, kg = ln >> 4;
  const int tbase = blockIdx.x * 128 + wv * 32;
  const int ar0 = min(tbase + lrow, NN - 1);
  const int ar1 = min(tbase + 16 + lrow, NN - 1);

  stage<2048>(WTl, wl, tid);
  stage<2048>(WTr, wr, tid);
  __syncthreads();

  f32x4 acc0[8], acc1[8];
#pragma unroll
  for (int cf = 0; cf < 8; ++cf) {
    acc0[cf] = (f32x4){0.f, 0.f, 0.f, 0.f};
    acc1[cf] = (f32x4){0.f, 0.f, 0.f, 0.f};
  }
#pragma unroll
  for (int ks = 0; ks < 4; ++ks) {
    const s16x8 g0 = *reinterpret_cast<const s16x8*>(agg + (size_t)ar0 * 128 + ks * 32 + kg * 8);
    const s16x8 g1 = *reinterpret_cast<const s16x8*>(agg + (size_t)ar1 * 128 + ks * 32 + kg * 8);
    const s16x8 h0 = *reinterpret_cast<const s16x8*>(hb + (size_t)ar0 * 128 + ks * 32 + kg * 8);
    const s16x8 h1 = *reinterpret_cast<const s16x8*>(hb + (size_t)ar1 * 128 + ks * 32 + kg * 8);
#pragma unroll
    for (int cf = 0; cf < 8; ++cf) {
      const s16x8 bwl = ldsw(wl, cf * 16 + lrow, ks * 4 + kg);
      const s16x8 bwr = ldsw(wr, cf * 16 + lrow, ks * 4 + kg);
      acc0[cf] = __builtin_amdgcn_mfma_f32_16x16x32_bf16(g0, bwl, acc0[cf], 0, 0, 0);
      acc0[cf] = __builtin_amdgcn_mfma_f32_16x16x32_bf16(h0, bwr, acc0[cf], 0, 0, 0);
      acc1[cf] = __builtin_amdgcn_mfma_f32_16x16x32_bf16(g1, bwl, acc1[cf], 0, 0, 0);
      acc1[cf] = __builtin_amdgcn_mfma_f32_16x16x32_bf16(h1, bwr, acc1[cf], 0, 0, 0);
    }
  }

  float bb[8], gm[8], gb[8];
#pragma unroll
  for (int cf = 0; cf < 8; ++cf) {
    const int c = cf * 16 + lrow;
    bb[cf] = bl[c];
    gm[cf] = lg[c];
    gb[cf] = lb[c];
  }
#pragma unroll
  for (int t = 0; t < 2; ++t)
#pragma unroll
    for (int j = 0; j < 4; ++j) {
      const int r = tbase + t * 16 + kg * 4 + j;
      const int rs = r < NN ? r : NN - 1;
      float v[8];
#pragma unroll
      for (int cf = 0; cf < 8; ++cf) {
        const int c = cf * 16 + lrow;
        v[cf] = b2f(hb[(size_t)rs * 128 + c]) +
                fmaxf((t ? acc1[cf][j] : acc0[cf][j]) + bb[cf], 0.0f);
      }
      float s = 0.f;
#pragma unroll
      for (int cf = 0; cf < 8; ++cf) s += v[cf];
      s += __shfl_xor(s, 1); s += __shfl_xor(s, 2);
      s += __shfl_xor(s, 4); s += __shfl_xor(s, 8);
      const float mu = s * (1.0f / 128);
      float q = 0.f;
#pragma unroll
      for (int cf = 0; cf < 8; ++cf) { const float d = v[cf] - mu; q += d * d; }
      q += __shfl_xor(q, 1); q += __shfl_xor(q, 2);
      q += __shfl_xor(q, 4); q += __shfl_xor(q, 8);
      const float istd = rsqrtf(q * (1.0f / 128) + 1e-5f);
      if (r < NN) {
#pragma unroll
        for (int cf = 0; cf < 8; ++cf)
          hb_out[(size_t)r * 128 + cf * 16 + lrow] = f2b((v[cf] - mu) * istd * gm[cf] + gb[cf]);
      }
    }
}

// ---------------- SAGE layer 1 + classifier fused ----------------
// LDS: [0,16384)=WTl -> th tile; [16384,32768)=WTr -> Wc1; [32768,37888)=Wc2
__global__ __launch_bounds__(256) void k_sage_cls(
    const u16* __restrict__ agg, const u16* __restrict__ hb,
    const u16* __restrict__ WTl, const u16* __restrict__ WTr,
    const float* __restrict__ bl, const float* __restrict__ lg,
    const float* __restrict__ lb,
    const u16* __restrict__ Wc1, const float* __restrict__ cb1,
    const u16* __restrict__ Wc2, const float* __restrict__ cb2,
    float* __restrict__ out_h, float* __restrict__ logits) {
  __shared__ u16 lds[37888];
  u16* wl = lds;          // phase A: WTl ; phase B: th tile (128x128)
  u16* wr = lds + 16384;  // phase A: WTr ; phase B: Wc1
  u16* w2 = lds + 32768;  // Wc2 (40x128)
  const int tid = threadIdx.x;
  const int wv = tid >> 6, ln = tid & 63;
  const int lrow = ln & 15, kg = ln >> 4;
  const int tbase = blockIdx.x * 128 + wv * 32;
  const int lb0 = wv * 32;
  const int ar0 = min(tbase + lrow, NN - 1);
  const int ar1 = min(tbase + 16 + lrow, NN - 1);

  stage<2048>(WTl, wl, tid);
  stage<2048>(WTr, wr, tid);
  stage<640>(Wc2, w2, tid);
  __syncthreads();

  f32x4 acc0[8], acc1[8];
#pragma unroll
  for (int cf = 0; cf < 8; ++cf) {
    acc0[cf] = (f32x4){0.f, 0.f, 0.f, 0.f};
    acc1[cf] = (f32x4){0.f, 0.f, 0.f, 0.f};
  }
#pragma unroll
  for (int ks = 0; ks < 4; ++ks) {
    const s16x8 g0 = *reinterpret_cast<const s16x8*>(agg + (size_t)ar0 * 128 + ks * 32 + kg * 8);
    const s16x8 g1 = *reinterpret_cast<const s16x8*>(agg + (size_t)ar1 * 128 + ks * 32 + kg * 8);
    const s16x8 h0 = *reinterpret_cast<const s16x8*>(hb + (size_t)ar0 * 128 + ks * 32 + kg * 8);
    const s16x8 h1 = *reinterpret_cast<const s16x8*>(hb + (size_t)ar1 * 128 + ks * 32 + kg * 8);
#pragma unroll
    for (int cf = 0; cf < 8; ++cf) {
      const s16x8 bwl = ldsw(wl, cf * 16 + lrow, ks * 4 + kg);
      const s16x8 bwr = ldsw(wr, cf * 16 + lrow, ks * 4 + kg);
      acc0[cf] = __builtin_amdgcn_mfma_f32_16x16x32_bf16(g0, bwl, acc0[cf], 0, 0, 0);
      acc0[cf] = __builtin_amdgcn_mfma_f32_16x16x32_bf16(h0, bwr, acc0[cf], 0, 0, 0);
      acc1[cf] = __builtin_amdgcn_mfma_f32_16x16x32_bf16(g1, bwl, acc1[cf], 0, 0, 0);
      acc1[cf] = __builtin_amdgcn_mfma_f32_16x16x32_bf16(h1, bwr, acc1[cf], 0, 0, 0);
    }
  }
  __syncthreads();  // all waves done reading WTl/WTr

  {
    float bb[8], gm[8], gb[8];
#pragma unroll
    for (int cf = 0; cf < 8; ++cf) {
      const int c = cf * 16 + lrow;
      bb[cf] = bl[c];
      gm[cf] = lg[c];
      gb[cf] = lb[c];
    }
#pragma unroll
    for (int t = 0; t < 2; ++t)
#pragma unroll
      for (int j = 0; j < 4; ++j) {
        const int r = tbase + t * 16 + kg * 4 + j;
        const int rs = r < NN ? r : NN - 1;
        const int lr = lb0 + t * 16 + kg * 4 + j;
        float v[8];
#pragma unroll
        for (int cf = 0; cf < 8; ++cf) {
          const int c = cf * 16 + lrow;
          v[cf] = b2f(hb[(size_t)rs * 128 + c]) +
                  fmaxf((t ? acc1[cf][j] : acc0[cf][j]) + bb[cf], 0.0f);
        }
        float s = 0.f;
#pragma unroll
        for (int cf = 0; cf < 8; ++cf) s += v[cf];
        s += __shfl_xor(s, 1); s += __shfl_xor(s, 2);
        s += __shfl_xor(s, 4); s += __shfl_xor(s, 8);
        const float mu = s * (1.0f / 128);
        float q = 0.f;
#pragma unroll
        for (int cf = 0; cf < 8; ++cf) { const float d = v[cf] - mu; q += d * d; }
        q += __shfl_xor(q, 1); q += __shfl_xor(q, 2);
        q += __shfl_xor(q, 4); q += __shfl_xor(q, 8);
        const float istd = rsqrtf(q * (1.0f / 128) + 1e-5f);
#pragma unroll
        for (int cf = 0; cf < 8; ++cf) {
          const int c = cf * 16 + lrow;
          const float o = (v[cf] - mu) * istd * gm[cf] + gb[cf];
          stsw(wl, lr, c, f2b(o));
          if (r < NN) out_h[(size_t)r * 128 + c] = o;
        }
      }
  }
  stage<2048>(Wc1, wr, tid);  // Wc1 over WTr (all reads done at barrier above)
  __syncthreads();

  // classifier: per wave, its own two 16-row th tiles
  float cb1v[8];
#pragma unroll
  for (int cf = 0; cf < 8; ++cf) cb1v[cf] = cb1[cf * 16 + lrow];

#pragma unroll
  for (int t = 0; t < 2; ++t) {
    const int rb = lb0 + t * 16;
    f32x4 a3[8];
#pragma unroll
    for (int cf = 0; cf < 8; ++cf) a3[cf] = (f32x4){0.f, 0.f, 0.f, 0.f};
#pragma unroll
    for (int ks = 0; ks < 4; ++ks) {
      const s16x8 a = ldsw(wl, rb + lrow, ks * 4 + kg);
#pragma unroll
      for (int cf = 0; cf < 8; ++cf) {
        const s16x8 bf = ldsw(wr, cf * 16 + lrow, ks * 4 + kg);
        a3[cf] = __builtin_amdgcn_mfma_f32_16x16x32_bf16(a, bf, a3[cf], 0, 0, 0);
      }
    }
    // t3 overwrites this wave's own th rows
#pragma unroll
    for (int j = 0; j < 4; ++j)
#pragma unroll
      for (int cf = 0; cf < 8; ++cf)
        stsw(wl, rb + kg * 4 + j, cf * 16 + lrow, f2b(fmaxf(a3[cf][j] + cb1v[cf], 0.0f)));

    f32x4 a2[3];
#pragma unroll
    for (int cf = 0; cf < 3; ++cf) a2[cf] = (f32x4){0.f, 0.f, 0.f, 0.f};
#pragma unroll
    for (int ks = 0; ks < 4; ++ks) {
      const s16x8 a = ldsw(wl, rb + lrow, ks * 4 + kg);
#pragma unroll
      for (int cf = 0; cf < 3; ++cf) {
        const int bn = min(cf * 16 + lrow, CC - 1);
        const s16x8 bf = ldsw(w2, bn, ks * 4 + kg);
        a2[cf] = __builtin_amdgcn_mfma_f32_16x16x32_bf16(a, bf, a2[cf], 0, 0, 0);
      }
    }
#pragma unroll
    for (int j = 0; j < 4; ++j) {
      const int r = tbase + t * 16 + kg * 4 + j;
      if (r < NN) {
#pragma unroll
        for (int cf = 0; cf < 3; ++cf) {
          const int c = cf * 16 + lrow;
          if (c < CC) logits[(size_t)r * CC + c] = a2[cf][j] + cb2[c];
        }
      }
    }
  }
}

}  // namespace

extern "C" void kernel_launch(void* const* d_in, const int* in_sizes, int n_in,
                              void* d_out, int out_size, void* d_ws, size_t ws_size,
                              hipStream_t stream) {
  (void)in_sizes; (void)n_in; (void)out_size; (void)ws_size;
  const float* x   = (const float*)d_in[0];
  const int*   ei  = (const int*)d_in[1];
  const float* pw1 = (const float*)d_in[2];
  const float* pb1 = (const float*)d_in[3];
  const float* pw2 = (const float*)d_in[4];
  const float* pb2 = (const float*)d_in[5];
  const float* ing = (const float*)d_in[6];
  const float* inb = (const float*)d_in[7];
  const float* swl = (const float*)d_in[8];
  const float* sbl = (const float*)d_in[9];
  const float* swr = (const float*)d_in[10];
  const float* lng = (const float*)d_in[11];
  const float* lnb = (const float*)d_in[12];
  const float* cw1 = (const float*)d_in[13];
  const float* cb1 = (const float*)d_in[14];
  const float* cw2 = (const float*)d_in[15];
  const float* cb2 = (const float*)d_in[16];

  float* out_logits = (float*)d_out;
  float* out_h = out_logits + (size_t)NN * CC;

  const size_t NNH = (size_t)NN * HH;
  u16*   hb   = (u16*)d_ws;                // 12.8 MB
  u16*   bufA = hb + NNH;                  // 12.8 MB (agg)
  u16*   wt   = bufA + NNH;                // 256 KB
  int*   cnt    = (int*)(wt + 8 * 16384);  // NN
  float* inv    = (float*)(cnt + NN);      // NN
  int*   rowptr = (int*)(inv + NN);        // NN+1
  int*   bsum   = rowptr + NN + 1;         // 256
  int*   colarr = bsum + 256;              // EE
  int*   rankar = colarr + EE;             // EE

  // ---- prelude: weight transpose + cnt zero (one dispatch) ----
  const int PRE_B = (7 * 16384 + CC * 128 + NN + 255) / 256;
  k_pre<<<PRE_B, 256, 0, stream>>>(pw1, pw2, swl, swr, cw1, cw2, wt, cnt);

  // ---- input MLP with degree histogram ridden in (independent work) ----
  k_mlp_deg<<<MG + DEGB, 256, 0, stream>>>(
      x, wt + 0 * 16384, pb1, wt + 1 * 16384, pb2, ing, inb, hb, ei, cnt, rankar);

  // ---- CSR scan + atomic-free fill ----
  k_scan_block<<<SCAN_NB, 256, 0, stream>>>(cnt, rowptr, bsum, inv);
  k_scan_add<<<SCAN_NB, 256, 0, stream>>>(rowptr, bsum);
  k_fill<<<(EE + 255) / 256, 256, 0, stream>>>(ei, rowptr, rankar, colarr);

  // layer 0
  k_gather_q<<<(NN + 15) / 16, 256, 0, stream>>>(hb, rowptr, colarr, inv, bufA);
  k_sage0<<<(NN + 127) / 128, 256, 0, stream>>>(
      bufA, hb, wt + 2 * 16384, wt + 4 * 16384, sbl, lng, lnb, hb);

  // layer 1 + classifier
  k_gather_q<<<(NN + 15) / 16, 256, 0, stream>>>(hb, rowptr, colarr, inv, bufA);
  k_sage_cls<<<(NN + 127) / 128, 256, 0, stream>>>(
      bufA, hb, wt + 3 * 16384, wt + 5 * 16384, sbl + HH, lng + HH, lnb + HH,
      wt + 6 * 16384, cb1, wt + 7 * 16384, cb2, out_h, out_logits);
}

// Round 13
// 142.952 us; speedup vs baseline: 1.5329x; 1.0744x over previous
//
#include <hip/hip_runtime.h>

// GNN encoder: input MLP + LN, 2x SAGEConv(mean) + ReLU + residual + LN, classifier MLP.
// Round 13 (base = round 12): fp8 gather path.
//  - producers (k_mlp_deg, k_sage0) also emit h8 (fp8 e4m3, lane-permuted layout:
//    pos lrow*8+cf holds col cf*16+lrow) via v_cvt_pk_fp8_f32 -> coalesced 8B stores
//  - k_gather8 reads 8B/lane (half of bf16), cvt_pk_f32_fp8, f32 accum, bf16 agg out
//  - weight-prep slots 2..7 ride inside k_mlp_deg (3rd domain); k_pre = slots 0,1 + zero

namespace {

constexpr int NN = 50000;
constexpr int EE = 640000;
constexpr int HH = 128;
constexpr int CC = 40;
constexpr int SCAN_NB = (NN + 255) / 256;  // 196
constexpr int MG = (NN + 127) / 128;       // 391 (mlp blocks)
constexpr int DEGB = (EE + 255) / 256;     // 2500 (degree blocks)
constexpr int WPB = (5 * 16384 + CC * 128 + 255) / 256;  // 340 (wt slots 2..7)

typedef unsigned short u16;
typedef __attribute__((ext_vector_type(8))) short s16x8;
typedef __attribute__((ext_vector_type(8))) unsigned short u16x8;
typedef __attribute__((ext_vector_type(4))) float f32x4;
typedef __attribute__((ext_vector_type(2))) float f32x2;

__device__ __forceinline__ float b2f(u16 h) {
  unsigned int u = ((unsigned int)h) << 16;
  return __builtin_bit_cast(float, u);
}
__device__ __forceinline__ u16 f2b(float f) {
  unsigned int u = __builtin_bit_cast(unsigned int, f);
  u += 0x7FFFu + ((u >> 16) & 1u);
  return (u16)(u >> 16);
}

// pack 8 floats -> 8 fp8 e4m3 bytes (v[q] -> byte q)
__device__ __forceinline__ uint2 pack_fp8(const float* v) {
  int w0 = 0, w1 = 0;
  w0 = __builtin_amdgcn_cvt_pk_fp8_f32(v[0], v[1], w0, false);
  w0 = __builtin_amdgcn_cvt_pk_fp8_f32(v[2], v[3], w0, true);
  w1 = __builtin_amdgcn_cvt_pk_fp8_f32(v[4], v[5], w1, false);
  w1 = __builtin_amdgcn_cvt_pk_fp8_f32(v[6], v[7], w1, true);
  return make_uint2((unsigned)w0, (unsigned)w1);
}
// accumulate 8 fp8 bytes into a[0..7]
__device__ __forceinline__ void acc_fp8(float* a, uint2 p) {
  const f32x2 f0 = __builtin_amdgcn_cvt_pk_f32_fp8((int)p.x, false);
  const f32x2 f1 = __builtin_amdgcn_cvt_pk_f32_fp8((int)p.x, true);
  const f32x2 f2 = __builtin_amdgcn_cvt_pk_f32_fp8((int)p.y, false);
  const f32x2 f3 = __builtin_amdgcn_cvt_pk_f32_fp8((int)p.y, true);
  a[0] += f0.x; a[1] += f0.y; a[2] += f1.x; a[3] += f1.y;
  a[4] += f2.x; a[5] += f2.y; a[6] += f3.x; a[7] += f3.y;
}

// ---- swizzled LDS tile: row n, 16B-granule k0; slot = k0 ^ (n&15) ----
__device__ __forceinline__ s16x8 ldsw(const u16* base, int n, int k0) {
  return *reinterpret_cast<const s16x8*>(base + n * 128 + (((k0 ^ n) & 15) << 3));
}
__device__ __forceinline__ void stsw(u16* base, int r, int c, u16 v) {
  base[r * 128 + ((((c >> 3) ^ r) & 15) << 3) + (c & 7)] = v;
}
template <int NGRAN>
__device__ __forceinline__ void stage(const u16* __restrict__ src, u16* dst, int tid) {
#pragma unroll
  for (int i = 0; i < (NGRAN + 255) / 256; ++i) {
    const int gi = i * 256 + tid;
    if ((NGRAN & 255) == 0 || gi < NGRAN) {
      const int n = gi >> 4, k0 = gi & 15;
      const u16x8 v = *reinterpret_cast<const u16x8*>(src + gi * 8);
      *reinterpret_cast<u16x8*>(dst + n * 128 + (((k0 ^ n) & 15) << 3)) = v;
    }
  }
}

// ---------------- prelude: WT1/WT2 transpose + cnt zero ----------------
__global__ void k_pre(const float* __restrict__ pw1, const float* __restrict__ pw2,
                      u16* __restrict__ wt, int* __restrict__ cnt) {
  int flat = blockIdx.x * 256 + threadIdx.x;
  const int TWO = 2 * 16384;
  if (flat < TWO) {
    int id = flat >> 14;
    int off = flat & 16383;
    int n = off >> 7, k = off & 127;
    const float* s = id == 0 ? pw1 : pw2;
    wt[(size_t)id * 16384 + n * 128 + k] = f2b(s[k * 128 + n]);
  } else {
    int i = flat - TWO;
    if (i < NN) cnt[i] = 0;
  }
}

// ---------------- CSR scan / fill ----------------
__global__ void k_scan_block(const int* __restrict__ cnt, int* __restrict__ rowptr,
                             int* __restrict__ bsum, float* __restrict__ inv) {
  __shared__ int s[256];
  const int t = threadIdx.x;
  const int i = blockIdx.x * 256 + t;
  const int v = i < NN ? cnt[i] : 0;
  s[t] = v;
  __syncthreads();
  for (int off = 1; off < 256; off <<= 1) {
    int add = t >= off ? s[t - off] : 0;
    __syncthreads();
    s[t] += add;
    __syncthreads();
  }
  if (i < NN) {
    rowptr[i] = s[t] - v;
    inv[i] = v > 0 ? 1.0f / (float)v : 0.0f;
  }
  if (t == 255) bsum[blockIdx.x] = s[255];
}

__global__ void k_scan_add(int* __restrict__ rowptr, const int* __restrict__ bsum) {
  __shared__ int s[256];
  const int t = threadIdx.x;
  const int v = t < SCAN_NB ? bsum[t] : 0;
  s[t] = v;
  __syncthreads();
  for (int off = 1; off < 256; off <<= 1) {
    int add = t >= off ? s[t - off] : 0;
    __syncthreads();
    s[t] += add;
    __syncthreads();
  }
  const int boff = blockIdx.x == 0 ? 0 : s[blockIdx.x - 1];
  const int i = blockIdx.x * 256 + t;
  if (i < NN) rowptr[i] += boff;
  if (i == 0) rowptr[NN] = EE;
}

// atomic-free fill: position = rowptr[dst] + rank[e]
__global__ void k_fill(const int* __restrict__ ei, const int* __restrict__ rowptr,
                       const int* __restrict__ rank, int* __restrict__ col) {
  int e = blockIdx.x * 256 + threadIdx.x;
  if (e >= EE) return;
  const int d = ei[EE + e];
  col[rowptr[d] + rank[e]] = ei[e];
}

// ---------------- aggregation: fp8 reads, quarter-wave per node, 8 in flight ----------------
__global__ __launch_bounds__(256) void k_gather8(
    const unsigned char* __restrict__ h8, const int* __restrict__ rowptr,
    const int* __restrict__ col, const float* __restrict__ inv,
    u16* __restrict__ agg) {
  const int tid = threadIdx.x;
  const int node = blockIdx.x * 16 + (tid >> 4);
  if (node >= NN) return;
  const int ln = tid & 15;
  const int cl = ln * 8;
  const int start = rowptr[node];
  const int end = rowptr[node + 1];
  float a[8] = {0.f, 0.f, 0.f, 0.f, 0.f, 0.f, 0.f, 0.f};
  int i = start;
  for (; i + 8 <= end; i += 8) {
    const uint2 p0 = *reinterpret_cast<const uint2*>(&h8[(size_t)col[i] * 128 + cl]);
    const uint2 p1 = *reinterpret_cast<const uint2*>(&h8[(size_t)col[i + 1] * 128 + cl]);
    const uint2 p2 = *reinterpret_cast<const uint2*>(&h8[(size_t)col[i + 2] * 128 + cl]);
    const uint2 p3 = *reinterpret_cast<const uint2*>(&h8[(size_t)col[i + 3] * 128 + cl]);
    const uint2 p4 = *reinterpret_cast<const uint2*>(&h8[(size_t)col[i + 4] * 128 + cl]);
    const uint2 p5 = *reinterpret_cast<const uint2*>(&h8[(size_t)col[i + 5] * 128 + cl]);
    const uint2 p6 = *reinterpret_cast<const uint2*>(&h8[(size_t)col[i + 6] * 128 + cl]);
    const uint2 p7 = *reinterpret_cast<const uint2*>(&h8[(size_t)col[i + 7] * 128 + cl]);
    acc_fp8(a, p0); acc_fp8(a, p1); acc_fp8(a, p2); acc_fp8(a, p3);
    acc_fp8(a, p4); acc_fp8(a, p5); acc_fp8(a, p6); acc_fp8(a, p7);
  }
  if (i + 4 <= end) {
    const uint2 p0 = *reinterpret_cast<const uint2*>(&h8[(size_t)col[i] * 128 + cl]);
    const uint2 p1 = *reinterpret_cast<const uint2*>(&h8[(size_t)col[i + 1] * 128 + cl]);
    const uint2 p2 = *reinterpret_cast<const uint2*>(&h8[(size_t)col[i + 2] * 128 + cl]);
    const uint2 p3 = *reinterpret_cast<const uint2*>(&h8[(size_t)col[i + 3] * 128 + cl]);
    acc_fp8(a, p0); acc_fp8(a, p1); acc_fp8(a, p2); acc_fp8(a, p3);
    i += 4;
  }
  for (; i < end; ++i) {
    const uint2 p0 = *reinterpret_cast<const uint2*>(&h8[(size_t)col[i] * 128 + cl]);
    acc_fp8(a, p0);
  }
  const float sc = inv[node];
  // a[k] corresponds to real column k*16 + ln (permuted h8 layout)
#pragma unroll
  for (int k = 0; k < 8; ++k)
    agg[(size_t)node * 128 + k * 16 + ln] = f2b(a[k] * sc);
}

// ---------------- fused input MLP + riders (degree, wt slots 2..7) ----------------
__global__ __launch_bounds__(256) void k_mlp_deg(
    const float* __restrict__ x, const u16* __restrict__ WT1,
    const float* __restrict__ pb1, const u16* __restrict__ WT2,
    const float* __restrict__ pb2, const float* __restrict__ lg,
    const float* __restrict__ lb, u16* __restrict__ hb,
    unsigned char* __restrict__ h8,
    const int* __restrict__ ei, int* __restrict__ cnt, int* __restrict__ rank,
    const float* __restrict__ swl, const float* __restrict__ swr,
    const float* __restrict__ cw1, const float* __restrict__ cw2,
    u16* __restrict__ wt) {
  __shared__ u16 lds[32768];
  if (blockIdx.x >= MG) {
    const int rb = blockIdx.x - MG;
    if (rb < DEGB) {
      const int e = rb * 256 + threadIdx.x;
      if (e < EE) rank[e] = atomicAdd(&cnt[ei[EE + e]], 1);
    } else {
      const int flat = (rb - DEGB) * 256 + threadIdx.x;
      const int FIVE = 5 * 16384;
      if (flat < FIVE) {
        int id = flat >> 14;  // 0..4 -> slots 2..6
        int off = flat & 16383;
        int n = off >> 7, k = off & 127;
        const float* s;
        switch (id) {
          case 0: s = swl; break;
          case 1: s = swl + 16384; break;
          case 2: s = swr; break;
          case 3: s = swr + 16384; break;
          default: s = cw1; break;
        }
        wt[(size_t)(id + 2) * 16384 + n * 128 + k] = f2b(s[k * 128 + n]);
      } else {
        int off = flat - FIVE;
        if (off < CC * 128) {
          int n = off >> 7, k = off & 127;
          wt[(size_t)7 * 16384 + n * 128 + k] = f2b(cw2[k * CC + n]);
        }
      }
    }
    return;
  }
  u16* wreg = lds;
  u16* t1r = lds + 16384;
  const int tid = threadIdx.x;
  const int wv = tid >> 6, ln = tid & 63;
  const int lrow = ln & 15, kg = ln >> 4;
  const int tbase = blockIdx.x * 128 + wv * 32;
  const int lb0 = wv * 32;
  const int ar0 = min(tbase + lrow, NN - 1);
  const int ar1 = min(tbase + 16 + lrow, NN - 1);

  stage<2048>(WT1, wreg, tid);
  __syncthreads();

  f32x4 acc0[8], acc1[8];
#pragma unroll
  for (int cf = 0; cf < 8; ++cf) {
    acc0[cf] = (f32x4){0.f, 0.f, 0.f, 0.f};
    acc1[cf] = (f32x4){0.f, 0.f, 0.f, 0.f};
  }
#pragma unroll
  for (int ks = 0; ks < 4; ++ks) {
    const float4* p0 = reinterpret_cast<const float4*>(x + (size_t)ar0 * 128 + ks * 32 + kg * 8);
    const float4* p1 = reinterpret_cast<const float4*>(x + (size_t)ar1 * 128 + ks * 32 + kg * 8);
    float4 x0 = p0[0], x1 = p0[1], y0 = p1[0], y1 = p1[1];
    s16x8 a0, a1;
    a0[0] = (short)f2b(x0.x); a0[1] = (short)f2b(x0.y); a0[2] = (short)f2b(x0.z); a0[3] = (short)f2b(x0.w);
    a0[4] = (short)f2b(x1.x); a0[5] = (short)f2b(x1.y); a0[6] = (short)f2b(x1.z); a0[7] = (short)f2b(x1.w);
    a1[0] = (short)f2b(y0.x); a1[1] = (short)f2b(y0.y); a1[2] = (short)f2b(y0.z); a1[3] = (short)f2b(y0.w);
    a1[4] = (short)f2b(y1.x); a1[5] = (short)f2b(y1.y); a1[6] = (short)f2b(y1.z); a1[7] = (short)f2b(y1.w);
#pragma unroll
    for (int cf = 0; cf < 8; ++cf) {
      const s16x8 bf = ldsw(wreg, cf * 16 + lrow, ks * 4 + kg);
      acc0[cf] = __builtin_amdgcn_mfma_f32_16x16x32_bf16(a0, bf, acc0[cf], 0, 0, 0);
      acc1[cf] = __builtin_amdgcn_mfma_f32_16x16x32_bf16(a1, bf, acc1[cf], 0, 0, 0);
    }
  }
  {
    float bb[8];
#pragma unroll
    for (int cf = 0; cf < 8; ++cf) bb[cf] = pb1[cf * 16 + lrow];
#pragma unroll
    for (int t = 0; t < 2; ++t)
#pragma unroll
      for (int j = 0; j < 4; ++j) {
        const int lr = lb0 + t * 16 + kg * 4 + j;
#pragma unroll
        for (int cf = 0; cf < 8; ++cf)
          stsw(t1r, lr, cf * 16 + lrow, f2b(fmaxf((t ? acc1[cf][j] : acc0[cf][j]) + bb[cf], 0.0f)));
      }
  }
  __syncthreads();
  stage<2048>(WT2, wreg, tid);
  __syncthreads();

  f32x4 c0[8], c1[8];
#pragma unroll
  for (int cf = 0; cf < 8; ++cf) {
    c0[cf] = (f32x4){0.f, 0.f, 0.f, 0.f};
    c1[cf] = (f32x4){0.f, 0.f, 0.f, 0.f};
  }
#pragma unroll
  for (int ks = 0; ks < 4; ++ks) {
    const s16x8 a0 = ldsw(t1r, lb0 + lrow, ks * 4 + kg);
    const s16x8 a1 = ldsw(t1r, lb0 + 16 + lrow, ks * 4 + kg);
#pragma unroll
    for (int cf = 0; cf < 8; ++cf) {
      const s16x8 bf = ldsw(wreg, cf * 16 + lrow, ks * 4 + kg);
      c0[cf] = __builtin_amdgcn_mfma_f32_16x16x32_bf16(a0, bf, c0[cf], 0, 0, 0);
      c1[cf] = __builtin_amdgcn_mfma_f32_16x16x32_bf16(a1, bf, c1[cf], 0, 0, 0);
    }
  }

  float bb[8], gm[8], gb[8];
#pragma unroll
  for (int cf = 0; cf < 8; ++cf) {
    const int c = cf * 16 + lrow;
    bb[cf] = pb2[c];
    gm[cf] = lg[c];
    gb[cf] = lb[c];
  }
#pragma unroll
  for (int t = 0; t < 2; ++t)
#pragma unroll
    for (int j = 0; j < 4; ++j) {
      const int r = tbase + t * 16 + kg * 4 + j;
      float v[8];
#pragma unroll
      for (int cf = 0; cf < 8; ++cf) v[cf] = (t ? c1[cf][j] : c0[cf][j]) + bb[cf];
      float s = 0.f;
#pragma unroll
      for (int cf = 0; cf < 8; ++cf) s += v[cf];
      s += __shfl_xor(s, 1); s += __shfl_xor(s, 2);
      s += __shfl_xor(s, 4); s += __shfl_xor(s, 8);
      const float mu = s * (1.0f / 128);
      float q = 0.f;
#pragma unroll
      for (int cf = 0; cf < 8; ++cf) { const float d = v[cf] - mu; q += d * d; }
      q += __shfl_xor(q, 1); q += __shfl_xor(q, 2);
      q += __shfl_xor(q, 4); q += __shfl_xor(q, 8);
      const float istd = rsqrtf(q * (1.0f / 128) + 1e-5f);
      if (r < NN) {
        float ov[8];
#pragma unroll
        for (int cf = 0; cf < 8; ++cf) {
          ov[cf] = (v[cf] - mu) * istd * gm[cf] + gb[cf];
          hb[(size_t)r * 128 + cf * 16 + lrow] = f2b(ov[cf]);
        }
        *reinterpret_cast<uint2*>(&h8[(size_t)r * 128 + lrow * 8]) = pack_fp8(ov);
      }
    }
}

// ---------------- SAGE layer 0: h' = LN(h + relu(agg@WL + bl + h@WR)) -> hb, h8 ----------------
__global__ __launch_bounds__(256) void k_sage0(
    const u16* __restrict__ agg, const u16* __restrict__ hb,
    const u16* __restrict__ WTl, const u16* __restrict__ WTr,
    const float* __restrict__ bl, const float* __restrict__ lg,
    const float* __restrict__ lb, u16* __restrict__ hb_out,
    unsigned char* __restrict__ h8) {
  __shared__ u16 lds[32768];
  u16* wl = lds;
  u16* wr = lds + 16384;
  const int tid = threadIdx.x;
  const int wv = tid >> 6, ln = tid & 63;
  const int lrow = ln & 15, kg = ln >> 4;
  const int tbase = blockIdx.x * 128 + wv * 32;
  const int ar0 = min(tbase + lrow, NN - 1);
  const int ar1 = min(tbase + 16 + lrow, NN - 1);

  stage<2048>(WTl, wl, tid);
  stage<2048>(WTr, wr, tid);
  __syncthreads();

  f32x4 acc0[8], acc1[8];
#pragma unroll
  for (int cf = 0; cf < 8; ++cf) {
    acc0[cf] = (f32x4){0.f, 0.f, 0.f, 0.f};
    acc1[cf] = (f32x4){0.f, 0.f, 0.f, 0.f};
  }
#pragma unroll
  for (int ks = 0; ks < 4; ++ks) {
    const s16x8 g0 = *reinterpret_cast<const s16x8*>(agg + (size_t)ar0 * 128 + ks * 32 + kg * 8);
    const s16x8 g1 = *reinterpret_cast<const s16x8*>(agg + (size_t)ar1 * 128 + ks * 32 + kg * 8);
    const s16x8 h0 = *reinterpret_cast<const s16x8*>(hb + (size_t)ar0 * 128 + ks * 32 + kg * 8);
    const s16x8 h1 = *reinterpret_cast<const s16x8*>(hb + (size_t)ar1 * 128 + ks * 32 + kg * 8);
#pragma unroll
    for (int cf = 0; cf < 8; ++cf) {
      const s16x8 bwl = ldsw(wl, cf * 16 + lrow, ks * 4 + kg);
      const s16x8 bwr = ldsw(wr, cf * 16 + lrow, ks * 4 + kg);
      acc0[cf] = __builtin_amdgcn_mfma_f32_16x16x32_bf16(g0, bwl, acc0[cf], 0, 0, 0);
      acc0[cf] = __builtin_amdgcn_mfma_f32_16x16x32_bf16(h0, bwr, acc0[cf], 0, 0, 0);
      acc1[cf] = __builtin_amdgcn_mfma_f32_16x16x32_bf16(g1, bwl, acc1[cf], 0, 0, 0);
      acc1[cf] = __builtin_amdgcn_mfma_f32_16x16x32_bf16(h1, bwr, acc1[cf], 0, 0, 0);
    }
  }

  float bb[8], gm[8], gb[8];
#pragma unroll
  for (int cf = 0; cf < 8; ++cf) {
    const int c = cf * 16 + lrow;
    bb[cf] = bl[c];
    gm[cf] = lg[c];
    gb[cf] = lb[c];
  }
#pragma unroll
  for (int t = 0; t < 2; ++t)
#pragma unroll
    for (int j = 0; j < 4; ++j) {
      const int r = tbase + t * 16 + kg * 4 + j;
      const int rs = r < NN ? r : NN - 1;
      float v[8];
#pragma unroll
      for (int cf = 0; cf < 8; ++cf) {
        const int c = cf * 16 + lrow;
        v[cf] = b2f(hb[(size_t)rs * 128 + c]) +
                fmaxf((t ? acc1[cf][j] : acc0[cf][j]) + bb[cf], 0.0f);
      }
      float s = 0.f;
#pragma unroll
      for (int cf = 0; cf < 8; ++cf) s += v[cf];
      s += __shfl_xor(s, 1); s += __shfl_xor(s, 2);
      s += __shfl_xor(s, 4); s += __shfl_xor(s, 8);
      const float mu = s * (1.0f / 128);
      float q = 0.f;
#pragma unroll
      for (int cf = 0; cf < 8; ++cf) { const float d = v[cf] - mu; q += d * d; }
      q += __shfl_xor(q, 1); q += __shfl_xor(q, 2);
      q += __shfl_xor(q, 4); q += __shfl_xor(q, 8);
      const float istd = rsqrtf(q * (1.0f / 128) + 1e-5f);
      if (r < NN) {
        float ov[8];
#pragma unroll
        for (int cf = 0; cf < 8; ++cf) {
          ov[cf] = (v[cf] - mu) * istd * gm[cf] + gb[cf];
          hb_out[(size_t)r * 128 + cf * 16 + lrow] = f2b(ov[cf]);
        }
        *reinterpret_cast<uint2*>(&h8[(size_t)r * 128 + lrow * 8]) = pack_fp8(ov);
      }
    }
}

// ---------------- SAGE layer 1 + classifier fused ----------------
// LDS: [0,16384)=WTl -> th tile; [16384,32768)=WTr -> Wc1; [32768,37888)=Wc2
__global__ __launch_bounds__(256) void k_sage_cls(
    const u16* __restrict__ agg, const u16* __restrict__ hb,
    const u16* __restrict__ WTl, const u16* __restrict__ WTr,
    const float* __restrict__ bl, const float* __restrict__ lg,
    const float* __restrict__ lb,
    const u16* __restrict__ Wc1, const float* __restrict__ cb1,
    const u16* __restrict__ Wc2, const float* __restrict__ cb2,
    float* __restrict__ out_h, float* __restrict__ logits) {
  __shared__ u16 lds[37888];
  u16* wl = lds;          // phase A: WTl ; phase B: th tile (128x128)
  u16* wr = lds + 16384;  // phase A: WTr ; phase B: Wc1
  u16* w2 = lds + 32768;  // Wc2 (40x128)
  const int tid = threadIdx.x;
  const int wv = tid >> 6, ln = tid & 63;
  const int lrow = ln & 15, kg = ln >> 4;
  const int tbase = blockIdx.x * 128 + wv * 32;
  const int lb0 = wv * 32;
  const int ar0 = min(tbase + lrow, NN - 1);
  const int ar1 = min(tbase + 16 + lrow, NN - 1);

  stage<2048>(WTl, wl, tid);
  stage<2048>(WTr, wr, tid);
  stage<640>(Wc2, w2, tid);
  __syncthreads();

  f32x4 acc0[8], acc1[8];
#pragma unroll
  for (int cf = 0; cf < 8; ++cf) {
    acc0[cf] = (f32x4){0.f, 0.f, 0.f, 0.f};
    acc1[cf] = (f32x4){0.f, 0.f, 0.f, 0.f};
  }
#pragma unroll
  for (int ks = 0; ks < 4; ++ks) {
    const s16x8 g0 = *reinterpret_cast<const s16x8*>(agg + (size_t)ar0 * 128 + ks * 32 + kg * 8);
    const s16x8 g1 = *reinterpret_cast<const s16x8*>(agg + (size_t)ar1 * 128 + ks * 32 + kg * 8);
    const s16x8 h0 = *reinterpret_cast<const s16x8*>(hb + (size_t)ar0 * 128 + ks * 32 + kg * 8);
    const s16x8 h1 = *reinterpret_cast<const s16x8*>(hb + (size_t)ar1 * 128 + ks * 32 + kg * 8);
#pragma unroll
    for (int cf = 0; cf < 8; ++cf) {
      const s16x8 bwl = ldsw(wl, cf * 16 + lrow, ks * 4 + kg);
      const s16x8 bwr = ldsw(wr, cf * 16 + lrow, ks * 4 + kg);
      acc0[cf] = __builtin_amdgcn_mfma_f32_16x16x32_bf16(g0, bwl, acc0[cf], 0, 0, 0);
      acc0[cf] = __builtin_amdgcn_mfma_f32_16x16x32_bf16(h0, bwr, acc0[cf], 0, 0, 0);
      acc1[cf] = __builtin_amdgcn_mfma_f32_16x16x32_bf16(g1, bwl, acc1[cf], 0, 0, 0);
      acc1[cf] = __builtin_amdgcn_mfma_f32_16x16x32_bf16(h1, bwr, acc1[cf], 0, 0, 0);
    }
  }
  __syncthreads();  // all waves done reading WTl/WTr

  {
    float bb[8], gm[8], gb[8];
#pragma unroll
    for (int cf = 0; cf < 8; ++cf) {
      const int c = cf * 16 + lrow;
      bb[cf] = bl[c];
      gm[cf] = lg[c];
      gb[cf] = lb[c];
    }
#pragma unroll
    for (int t = 0; t < 2; ++t)
#pragma unroll
      for (int j = 0; j < 4; ++j) {
        const int r = tbase + t * 16 + kg * 4 + j;
        const int rs = r < NN ? r : NN - 1;
        const int lr = lb0 + t * 16 + kg * 4 + j;
        float v[8];
#pragma unroll
        for (int cf = 0; cf < 8; ++cf) {
          const int c = cf * 16 + lrow;
          v[cf] = b2f(hb[(size_t)rs * 128 + c]) +
                  fmaxf((t ? acc1[cf][j] : acc0[cf][j]) + bb[cf], 0.0f);
        }
        float s = 0.f;
#pragma unroll
        for (int cf = 0; cf < 8; ++cf) s += v[cf];
        s += __shfl_xor(s, 1); s += __shfl_xor(s, 2);
        s += __shfl_xor(s, 4); s += __shfl_xor(s, 8);
        const float mu = s * (1.0f / 128);
        float q = 0.f;
#pragma unroll
        for (int cf = 0; cf < 8; ++cf) { const float d = v[cf] - mu; q += d * d; }
        q += __shfl_xor(q, 1); q += __shfl_xor(q, 2);
        q += __shfl_xor(q, 4); q += __shfl_xor(q, 8);
        const float istd = rsqrtf(q * (1.0f / 128) + 1e-5f);
#pragma unroll
        for (int cf = 0; cf < 8; ++cf) {
          const int c = cf * 16 + lrow;
          const float o = (v[cf] - mu) * istd * gm[cf] + gb[cf];
          stsw(wl, lr, c, f2b(o));
          if (r < NN) out_h[(size_t)r * 128 + c] = o;
        }
      }
  }
  stage<2048>(Wc1, wr, tid);  // Wc1 over WTr (all reads done at barrier above)
  __syncthreads();

  // classifier: per wave, its own two 16-row th tiles
  float cb1v[8];
#pragma unroll
  for (int cf = 0; cf < 8; ++cf) cb1v[cf] = cb1[cf * 16 + lrow];

#pragma unroll
  for (int t = 0; t < 2; ++t) {
    const int rb = lb0 + t * 16;
    f32x4 a3[8];
#pragma unroll
    for (int cf = 0; cf < 8; ++cf) a3[cf] = (f32x4){0.f, 0.f, 0.f, 0.f};
#pragma unroll
    for (int ks = 0; ks < 4; ++ks) {
      const s16x8 a = ldsw(wl, rb + lrow, ks * 4 + kg);
#pragma unroll
      for (int cf = 0; cf < 8; ++cf) {
        const s16x8 bf = ldsw(wr, cf * 16 + lrow, ks * 4 + kg);
        a3[cf] = __builtin_amdgcn_mfma_f32_16x16x32_bf16(a, bf, a3[cf], 0, 0, 0);
      }
    }
    // t3 overwrites this wave's own th rows
#pragma unroll
    for (int j = 0; j < 4; ++j)
#pragma unroll
      for (int cf = 0; cf < 8; ++cf)
        stsw(wl, rb + kg * 4 + j, cf * 16 + lrow, f2b(fmaxf(a3[cf][j] + cb1v[cf], 0.0f)));

    f32x4 a2[3];
#pragma unroll
    for (int cf = 0; cf < 3; ++cf) a2[cf] = (f32x4){0.f, 0.f, 0.f, 0.f};
#pragma unroll
    for (int ks = 0; ks < 4; ++ks) {
      const s16x8 a = ldsw(wl, rb + lrow, ks * 4 + kg);
#pragma unroll
      for (int cf = 0; cf < 3; ++cf) {
        const int bn = min(cf * 16 + lrow, CC - 1);
        const s16x8 bf = ldsw(w2, bn, ks * 4 + kg);
        a2[cf] = __builtin_amdgcn_mfma_f32_16x16x32_bf16(a, bf, a2[cf], 0, 0, 0);
      }
    }
#pragma unroll
    for (int j = 0; j < 4; ++j) {
      const int r = tbase + t * 16 + kg * 4 + j;
      if (r < NN) {
#pragma unroll
        for (int cf = 0; cf < 3; ++cf) {
          const int c = cf * 16 + lrow;
          if (c < CC) logits[(size_t)r * CC + c] = a2[cf][j] + cb2[c];
        }
      }
    }
  }
}

}  // namespace

extern "C" void kernel_launch(void* const* d_in, const int* in_sizes, int n_in,
                              void* d_out, int out_size, void* d_ws, size_t ws_size,
                              hipStream_t stream) {
  (void)in_sizes; (void)n_in; (void)out_size; (void)ws_size;
  const float* x   = (const float*)d_in[0];
  const int*   ei  = (const int*)d_in[1];
  const float* pw1 = (const float*)d_in[2];
  const float* pb1 = (const float*)d_in[3];
  const float* pw2 = (const float*)d_in[4];
  const float* pb2 = (const float*)d_in[5];
  const float* ing = (const float*)d_in[6];
  const float* inb = (const float*)d_in[7];
  const float* swl = (const float*)d_in[8];
  const float* sbl = (const float*)d_in[9];
  const float* swr = (const float*)d_in[10];
  const float* lng = (const float*)d_in[11];
  const float* lnb = (const float*)d_in[12];
  const float* cw1 = (const float*)d_in[13];
  const float* cb1 = (const float*)d_in[14];
  const float* cw2 = (const float*)d_in[15];
  const float* cb2 = (const float*)d_in[16];

  float* out_logits = (float*)d_out;
  float* out_h = out_logits + (size_t)NN * CC;

  const size_t NNH = (size_t)NN * HH;
  u16*   hb   = (u16*)d_ws;                // 12.8 MB
  u16*   bufA = hb + NNH;                  // 12.8 MB (agg)
  u16*   wt   = bufA + NNH;                // 256 KB
  int*   cnt    = (int*)(wt + 8 * 16384);  // NN
  float* inv    = (float*)(cnt + NN);      // NN
  int*   rowptr = (int*)(inv + NN);        // NN+1
  int*   bsum   = rowptr + NN + 1;         // 256
  int*   colarr = bsum + 256;              // EE
  int*   rankar = colarr + EE;             // EE
  unsigned char* h8 = (unsigned char*)(rankar + EE);  // NN*128 bytes (fp8)

  // ---- prelude: WT1/WT2 transpose + cnt zero ----
  const int PRE_B = (2 * 16384 + NN + 255) / 256;
  k_pre<<<PRE_B, 256, 0, stream>>>(pw1, pw2, wt, cnt);

  // ---- input MLP with degree histogram + sage/cls weight-prep ridden in ----
  k_mlp_deg<<<MG + DEGB + WPB, 256, 0, stream>>>(
      x, wt + 0 * 16384, pb1, wt + 1 * 16384, pb2, ing, inb, hb, h8,
      ei, cnt, rankar, swl, swr, cw1, cw2, wt);

  // ---- CSR scan + atomic-free fill ----
  k_scan_block<<<SCAN_NB, 256, 0, stream>>>(cnt, rowptr, bsum, inv);
  k_scan_add<<<SCAN_NB, 256, 0, stream>>>(rowptr, bsum);
  k_fill<<<(EE + 255) / 256, 256, 0, stream>>>(ei, rowptr, rankar, colarr);

  // layer 0 (fp8 gather)
  k_gather8<<<(NN + 15) / 16, 256, 0, stream>>>(h8, rowptr, colarr, inv, bufA);
  k_sage0<<<(NN + 127) / 128, 256, 0, stream>>>(
      bufA, hb, wt + 2 * 16384, wt + 4 * 16384, sbl, lng, lnb, hb, h8);

  // layer 1 + classifier
  k_gather8<<<(NN + 15) / 16, 256, 0, stream>>>(h8, rowptr, colarr, inv, bufA);
  k_sage_cls<<<(NN + 127) / 128, 256, 0, stream>>>(
      bufA, hb, wt + 3 * 16384, wt + 5 * 16384, sbl + HH, lng + HH, lnb + HH,
      wt + 6 * 16384, cb1, wt + 7 * 16384, cb2, out_h, out_logits);
}